// Round 1
// baseline (610.310 us; speedup 1.0000x reference)
//
#include <hip/hip_runtime.h>

#define HEADS 4
#define CDIM  64
#define HD    256   // HEADS*CDIM
#define INDIM 128
#define NEG   0.2f

// monotone float<->uint map for atomicMax on floats
__device__ __forceinline__ unsigned fmap(float f) {
    unsigned u = __float_as_uint(f);
    return (u & 0x80000000u) ? ~u : (u | 0x80000000u);
}
__device__ __forceinline__ float funmap(unsigned u) {
    unsigned b = (u & 0x80000000u) ? (u & 0x7FFFFFFFu) : ~u;
    return __uint_as_float(b);
}

__device__ __forceinline__ float wave_sum(float v) {
#pragma unroll
    for (int o = 32; o > 0; o >>= 1) v += __shfl_xor(v, o, 64);
    return v;
}

// h = x @ W  (N x 128) @ (128 x 256), fused a_src/a_dst epilogue.
// 16 nodes per block, 256 threads (thread t = output column, wave = head).
__global__ __launch_bounds__(256) void gemm_proj(
    const float* __restrict__ x, const float* __restrict__ W,
    const float* __restrict__ att_src, const float* __restrict__ att_dst,
    float* __restrict__ h, float* __restrict__ a_src, float* __restrict__ a_dst,
    int N)
{
    __shared__ float xs[16][INDIM];
    const int t    = threadIdx.x;
    const int base = blockIdx.x * 16;

    // load 16x128 tile (float4, clamp row for tail safety)
    float4* xdst = (float4*)&xs[0][0];
    for (int i = t; i < 16 * INDIM / 4; i += 256) {
        int row  = i >> 5;          // 32 float4 per row
        int col4 = i & 31;
        int node = base + row; if (node >= N) node = N - 1;
        xdst[i] = ((const float4*)(x + (size_t)node * INDIM))[col4];
    }
    __syncthreads();

    const int c    = t;
    const int head = t >> 6;
    const int lane = t & 63;

    float acc[16];
#pragma unroll
    for (int m = 0; m < 16; ++m) acc[m] = 0.f;

    for (int k = 0; k < INDIM; ++k) {
        float wv = W[k * HD + c];
#pragma unroll
        for (int m = 0; m < 16; ++m) acc[m] = fmaf(xs[m][k], wv, acc[m]);
    }

    const float asw = att_src[head * CDIM + lane];
    const float adw = att_dst[head * CDIM + lane];
#pragma unroll
    for (int m = 0; m < 16; ++m) {
        int node = base + m;
        if (node >= N) break;
        h[(size_t)node * HD + c] = acc[m];
        float ss = wave_sum(acc[m] * asw);
        float sd = wave_sum(acc[m] * adw);
        if (lane == 0) {
            a_src[node * HEADS + head] = ss;
            a_dst[node * HEADS + head] = sd;
        }
    }
}

// pass 1: per-edge leaky-relu logits -> segment max via atomicMax(mapped)
__global__ void edge_max(const int* __restrict__ ei, int E, int Etot,
    const float4* __restrict__ a_src4, const float4* __restrict__ a_dst4,
    unsigned* __restrict__ amax)
{
    int e = blockIdx.x * blockDim.x + threadIdx.x;
    if (e >= Etot) return;
    int s, d;
    if (e < E) { s = ei[e]; d = ei[E + e]; } else { s = d = e - E; }
    float4 as = a_src4[s];
    float4 ad = a_dst4[d];
    float al[4] = {as.x + ad.x, as.y + ad.y, as.z + ad.z, as.w + ad.w};
#pragma unroll
    for (int hh = 0; hh < 4; ++hh) {
        float a = al[hh];
        a = a >= 0.f ? a : NEG * a;
        atomicMax(&amax[d * 4 + hh], fmap(a));
    }
}

// pass 2: e = exp(alpha - amax[dst]); store e; denom += e
__global__ void edge_exp(const int* __restrict__ ei, int E, int Etot,
    const float4* __restrict__ a_src4, const float4* __restrict__ a_dst4,
    const uint4* __restrict__ amax4,
    float4* __restrict__ evals, float* __restrict__ denom)
{
    int e = blockIdx.x * blockDim.x + threadIdx.x;
    if (e >= Etot) return;
    int s, d;
    if (e < E) { s = ei[e]; d = ei[E + e]; } else { s = d = e - E; }
    float4 as = a_src4[s];
    float4 ad = a_dst4[d];
    uint4  am = amax4[d];
    float al[4] = {as.x + ad.x, as.y + ad.y, as.z + ad.z, as.w + ad.w};
    float mx[4] = {funmap(am.x), funmap(am.y), funmap(am.z), funmap(am.w)};
    float ex[4];
#pragma unroll
    for (int hh = 0; hh < 4; ++hh) {
        float a = al[hh];
        a = a >= 0.f ? a : NEG * a;
        ex[hh] = expf(a - mx[hh]);
    }
    evals[e] = make_float4(ex[0], ex[1], ex[2], ex[3]);
#pragma unroll
    for (int hh = 0; hh < 4; ++hh) atomicAdd(&denom[d * 4 + hh], ex[hh]);
}

// pass 3: one wave per edge, lane = channel; fold head-mean (0.25) into the
// per-lane sum over heads -> 64 atomic floats per edge instead of 256.
__global__ __launch_bounds__(256) void edge_aggr(const int* __restrict__ ei,
    int E, int Etot,
    const float4* __restrict__ evals, const float4* __restrict__ denom4,
    const float* __restrict__ h, float* __restrict__ outacc)
{
    int wid  = (int)((blockIdx.x * (size_t)blockDim.x + threadIdx.x) >> 6);
    int lane = threadIdx.x & 63;
    if (wid >= Etot) return;
    int s, d;
    if (wid < E) { s = ei[wid]; d = ei[E + wid]; } else { s = d = wid - E; }
    float4 ev = evals[wid];
    float4 dn = denom4[d];
    float w0 = 0.25f * ev.x / dn.x;
    float w1 = 0.25f * ev.y / dn.y;
    float w2 = 0.25f * ev.z / dn.z;
    float w3 = 0.25f * ev.w / dn.w;
    const float* hs = h + (size_t)s * HD;
    float v = w0 * hs[lane] + w1 * hs[64 + lane] + w2 * hs[128 + lane] + w3 * hs[192 + lane];
    atomicAdd(&outacc[(size_t)d * CDIM + lane], v);
}

// finalize: one wave per node. bias + LayerNorm + PReLU, in-place on out.
__global__ __launch_bounds__(256) void finalize_ln(float* __restrict__ out,
    const float* __restrict__ bias, const float* __restrict__ gamma,
    const float* __restrict__ beta, const float* __restrict__ prelu, int N)
{
    int wid  = (int)((blockIdx.x * (size_t)blockDim.x + threadIdx.x) >> 6);
    int lane = threadIdx.x & 63;
    if (wid >= N) return;
    float v  = out[(size_t)wid * CDIM + lane] + bias[lane];
    float mu = wave_sum(v) * (1.f / 64.f);
    float df = v - mu;
    float var = wave_sum(df * df) * (1.f / 64.f);
    float rs = rsqrtf(var + 1e-5f);
    float o  = df * rs * gamma[lane] + beta[lane];
    float pw = prelu[0];
    o = o >= 0.f ? o : pw * o;
    out[(size_t)wid * CDIM + lane] = o;
}

extern "C" void kernel_launch(void* const* d_in, const int* in_sizes, int n_in,
                              void* d_out, int out_size, void* d_ws, size_t ws_size,
                              hipStream_t stream)
{
    const float* x       = (const float*)d_in[0];
    const int*   ei      = (const int*)  d_in[1];
    const float* W       = (const float*)d_in[2];
    const float* att_src = (const float*)d_in[3];
    const float* att_dst = (const float*)d_in[4];
    const float* bias    = (const float*)d_in[5];
    const float* gamma   = (const float*)d_in[6];
    const float* beta    = (const float*)d_in[7];
    const float* prelu   = (const float*)d_in[8];

    const int N    = in_sizes[0] / INDIM;
    const int E    = in_sizes[1] / 2;
    const int Etot = E + N;
    float* out = (float*)d_out;

    // workspace layout
    float*    h      = (float*)d_ws;                        // N*256
    float*    a_src  = h + (size_t)N * HD;                  // N*4
    float*    a_dst  = a_src + (size_t)N * HEADS;           // N*4
    unsigned* amax   = (unsigned*)(a_dst + (size_t)N * HEADS); // N*4
    float*    denom  = (float*)(amax + (size_t)N * HEADS);  // N*4
    float*    evals  = denom + (size_t)N * HEADS;           // Etot*4

    hipMemsetAsync(amax,  0, (size_t)N * HEADS * sizeof(unsigned), stream);
    hipMemsetAsync(denom, 0, (size_t)N * HEADS * sizeof(float),    stream);
    hipMemsetAsync(out,   0, (size_t)N * CDIM  * sizeof(float),    stream);

    gemm_proj<<<(N + 15) / 16, 256, 0, stream>>>(x, W, att_src, att_dst,
                                                 h, a_src, a_dst, N);

    int thr = 256;
    edge_max<<<(Etot + thr - 1) / thr, thr, 0, stream>>>(
        ei, E, Etot, (const float4*)a_src, (const float4*)a_dst, amax);

    edge_exp<<<(Etot + thr - 1) / thr, thr, 0, stream>>>(
        ei, E, Etot, (const float4*)a_src, (const float4*)a_dst,
        (const uint4*)amax, (float4*)evals, denom);

    // one wave (64 lanes) per edge
    size_t waves = (size_t)Etot;
    edge_aggr<<<(unsigned)((waves * 64 + 255) / 256), 256, 0, stream>>>(
        ei, E, Etot, (const float4*)evals, (const float4*)denom,
        h, out);

    finalize_ln<<<(N * 64 + 255) / 256, 256, 0, stream>>>(
        out, bias, gamma, beta, prelu, N);
}

// Round 2
// 475.356 us; speedup vs baseline: 1.2839x; 1.2839x over previous
//
#include <hip/hip_runtime.h>

#define HEADS 4
#define CDIM  64
#define INDIM 128
#define NEG   0.2f

__device__ __forceinline__ float wave_sum(float v) {
#pragma unroll
    for (int o = 32; o > 0; o >>= 1) v += __shfl_xor(v, o, 64);
    return v;
}

// pack two floats to bf16 pair (RNE), a -> low 16, b -> high 16
__device__ __forceinline__ unsigned pack_bf16(float a, float b) {
    unsigned ua = __float_as_uint(a);
    unsigned ub = __float_as_uint(b);
    ua = (ua + 0x7FFFu + ((ua >> 16) & 1u)) >> 16;
    ub = (ub + 0x7FFFu + ((ub >> 16) & 1u)) & 0xFFFF0000u;
    return ua | ub;
}
__device__ __forceinline__ float bf_lo(unsigned u) { return __uint_as_float(u << 16); }
__device__ __forceinline__ float bf_hi(unsigned u) { return __uint_as_float(u & 0xFFFF0000u); }

// h = x @ W  (N x 128) @ (128 x 256).
// 32 rows per block (8 per wave); thread owns channel `lane` of all 4 heads
// (cols lane, lane+64, lane+128, lane+192). No LDS: x rows are wave-uniform
// broadcast float4 loads, W rows are coalesced dword loads (L2-resident).
// Epilogue: bf16-pack h (uint2 per (node,channel) = 4 head values) and
// wave-reduce a_src/a_dst from the fp32 accumulators.
__global__ __launch_bounds__(256) void gemm_proj(
    const float* __restrict__ x, const float* __restrict__ W,
    const float* __restrict__ att_src, const float* __restrict__ att_dst,
    uint2* __restrict__ hp, float4* __restrict__ a_src4, float4* __restrict__ a_dst4,
    int N)
{
    const int t    = threadIdx.x;
    const int lane = t & 63;
    const int wv   = t >> 6;
    const int row0 = blockIdx.x * 32 + wv * 8;

    const float4* xp[8];
#pragma unroll
    for (int m = 0; m < 8; ++m) {
        int r = row0 + m; if (r >= N) r = N - 1;
        xp[m] = (const float4*)(x + (size_t)r * INDIM);
    }

    float acc[8][4];
#pragma unroll
    for (int m = 0; m < 8; ++m)
#pragma unroll
        for (int q = 0; q < 4; ++q) acc[m][q] = 0.f;

    for (int k4 = 0; k4 < 32; ++k4) {
        float wv4[4][4];
#pragma unroll
        for (int j = 0; j < 4; ++j) {
            const float* Wr = W + (size_t)(k4 * 4 + j) * 256 + lane;
            wv4[j][0] = Wr[0];
            wv4[j][1] = Wr[64];
            wv4[j][2] = Wr[128];
            wv4[j][3] = Wr[192];
        }
#pragma unroll
        for (int m = 0; m < 8; ++m) {
            float4 xv = xp[m][k4];
#pragma unroll
            for (int q = 0; q < 4; ++q) {
                acc[m][q] = fmaf(xv.x, wv4[0][q], acc[m][q]);
                acc[m][q] = fmaf(xv.y, wv4[1][q], acc[m][q]);
                acc[m][q] = fmaf(xv.z, wv4[2][q], acc[m][q]);
                acc[m][q] = fmaf(xv.w, wv4[3][q], acc[m][q]);
            }
        }
    }

    float asw[4], adw[4];
#pragma unroll
    for (int q = 0; q < 4; ++q) {
        asw[q] = att_src[q * CDIM + lane];
        adw[q] = att_dst[q * CDIM + lane];
    }

#pragma unroll
    for (int m = 0; m < 8; ++m) {
        int node = row0 + m;
        if (node >= N) break;
        float s0 = wave_sum(acc[m][0] * asw[0]);
        float s1 = wave_sum(acc[m][1] * asw[1]);
        float s2 = wave_sum(acc[m][2] * asw[2]);
        float s3 = wave_sum(acc[m][3] * asw[3]);
        float d0 = wave_sum(acc[m][0] * adw[0]);
        float d1 = wave_sum(acc[m][1] * adw[1]);
        float d2 = wave_sum(acc[m][2] * adw[2]);
        float d3 = wave_sum(acc[m][3] * adw[3]);
        hp[(size_t)node * CDIM + lane] =
            make_uint2(pack_bf16(acc[m][0], acc[m][1]), pack_bf16(acc[m][2], acc[m][3]));
        if (lane == 0) {
            a_src4[node] = make_float4(s0, s1, s2, s3);
            a_dst4[node] = make_float4(d0, d1, d2, d3);
        }
    }
}

// exp pass (no max subtraction: logits bounded, softmax is shift-invariant):
// e = exp(lrelu(a_src[s] + a_dst[d])), store e, denom += e
__global__ __launch_bounds__(256) void edge_exp(const int* __restrict__ ei,
    int E, int Etot,
    const float4* __restrict__ a_src4, const float4* __restrict__ a_dst4,
    float4* __restrict__ evals, float* __restrict__ denom)
{
    int e = blockIdx.x * 256 + threadIdx.x;
    if (e >= Etot) return;
    int s, d;
    if (e < E) { s = ei[e]; d = ei[E + e]; } else { s = d = e - E; }
    float4 as = a_src4[s];
    float4 ad = a_dst4[d];
    float al[4] = {as.x + ad.x, as.y + ad.y, as.z + ad.z, as.w + ad.w};
    float ex[4];
#pragma unroll
    for (int hh = 0; hh < 4; ++hh) {
        float a = al[hh];
        a = a >= 0.f ? a : NEG * a;
        ex[hh] = __expf(a);
    }
    evals[e] = make_float4(ex[0], ex[1], ex[2], ex[3]);
#pragma unroll
    for (int hh = 0; hh < 4; ++hh) atomicAdd(&denom[d * 4 + hh], ex[hh]);
}

// aggregation: one wave per edge, lane = channel. bf16-packed h gather:
// one uint2 = all 4 head values for this channel. Head-mean (0.25) folded in.
__global__ __launch_bounds__(256) void edge_aggr(const int* __restrict__ ei,
    int E, int Etot,
    const float4* __restrict__ evals, const float4* __restrict__ denom4,
    const uint2* __restrict__ hp, float* __restrict__ outacc)
{
    int wid  = (int)((blockIdx.x * (unsigned)blockDim.x + threadIdx.x) >> 6);
    int lane = threadIdx.x & 63;
    if (wid >= Etot) return;
    int s, d;
    if (wid < E) { s = ei[wid]; d = ei[E + wid]; } else { s = d = wid - E; }
    float4 ev = evals[wid];
    float4 dn = denom4[d];
    float w0 = 0.25f * ev.x * __builtin_amdgcn_rcpf(dn.x);
    float w1 = 0.25f * ev.y * __builtin_amdgcn_rcpf(dn.y);
    float w2 = 0.25f * ev.z * __builtin_amdgcn_rcpf(dn.z);
    float w3 = 0.25f * ev.w * __builtin_amdgcn_rcpf(dn.w);
    uint2 h2 = hp[s * CDIM + lane];
    float v = w0 * bf_lo(h2.x) + w1 * bf_hi(h2.x) + w2 * bf_lo(h2.y) + w3 * bf_hi(h2.y);
    atomicAdd(&outacc[((size_t)d << 6) + lane], v);
}

// finalize: one wave per node. bias + LayerNorm + PReLU, in-place on out.
__global__ __launch_bounds__(256) void finalize_ln(float* __restrict__ out,
    const float* __restrict__ bias, const float* __restrict__ gamma,
    const float* __restrict__ beta, const float* __restrict__ prelu, int N)
{
    int wid  = (int)((blockIdx.x * (unsigned)blockDim.x + threadIdx.x) >> 6);
    int lane = threadIdx.x & 63;
    if (wid >= N) return;
    float v  = out[(size_t)wid * CDIM + lane] + bias[lane];
    float mu = wave_sum(v) * (1.f / 64.f);
    float df = v - mu;
    float var = wave_sum(df * df) * (1.f / 64.f);
    float rs = rsqrtf(var + 1e-5f);
    float o  = df * rs * gamma[lane] + beta[lane];
    float pw = prelu[0];
    o = o >= 0.f ? o : pw * o;
    out[(size_t)wid * CDIM + lane] = o;
}

extern "C" void kernel_launch(void* const* d_in, const int* in_sizes, int n_in,
                              void* d_out, int out_size, void* d_ws, size_t ws_size,
                              hipStream_t stream)
{
    const float* x       = (const float*)d_in[0];
    const int*   ei      = (const int*)  d_in[1];
    const float* W       = (const float*)d_in[2];
    const float* att_src = (const float*)d_in[3];
    const float* att_dst = (const float*)d_in[4];
    const float* bias    = (const float*)d_in[5];
    const float* gamma   = (const float*)d_in[6];
    const float* beta    = (const float*)d_in[7];
    const float* prelu   = (const float*)d_in[8];

    const int N    = in_sizes[0] / INDIM;
    const int E    = in_sizes[1] / 2;
    const int Etot = E + N;
    float* out = (float*)d_out;

    // workspace layout
    uint2* hp    = (uint2*)d_ws;                                  // N*64 uint2 (25.6 MB)
    float* a_src = (float*)(hp + (size_t)N * CDIM);               // N*4
    float* a_dst = a_src + (size_t)N * HEADS;                     // N*4
    float* denom = a_dst + (size_t)N * HEADS;                     // N*4
    float* evals = denom + (size_t)N * HEADS;                     // Etot*4

    hipMemsetAsync(denom, 0, (size_t)N * HEADS * sizeof(float), stream);
    hipMemsetAsync(out,   0, (size_t)N * CDIM  * sizeof(float), stream);

    gemm_proj<<<(N + 31) / 32, 256, 0, stream>>>(
        x, W, att_src, att_dst, hp, (float4*)a_src, (float4*)a_dst, N);

    edge_exp<<<(Etot + 255) / 256, 256, 0, stream>>>(
        ei, E, Etot, (const float4*)a_src, (const float4*)a_dst,
        (float4*)evals, denom);

    edge_aggr<<<(unsigned)(((size_t)Etot * 64 + 255) / 256), 256, 0, stream>>>(
        ei, E, Etot, (const float4*)evals, (const float4*)denom,
        hp, out);

    finalize_ln<<<(N * 64 + 255) / 256, 256, 0, stream>>>(
        out, bias, gamma, beta, prelu, N);
}

// Round 3
// 389.761 us; speedup vs baseline: 1.5659x; 1.2196x over previous
//
#include <hip/hip_runtime.h>

#define HEADS 4
#define CDIM  64
#define INDIM 128
#define NEG   0.2f

__device__ __forceinline__ float wave_sum(float v) {
#pragma unroll
    for (int o = 32; o > 0; o >>= 1) v += __shfl_xor(v, o, 64);
    return v;
}

// pack two floats to bf16 pair (RNE), a -> low 16, b -> high 16
__device__ __forceinline__ unsigned pack_bf16(float a, float b) {
    unsigned ua = __float_as_uint(a);
    unsigned ub = __float_as_uint(b);
    ua = (ua + 0x7FFFu + ((ua >> 16) & 1u)) >> 16;
    ub = (ub + 0x7FFFu + ((ub >> 16) & 1u)) & 0xFFFF0000u;
    return ua | ub;
}
__device__ __forceinline__ float bf_lo(unsigned u) { return __uint_as_float(u << 16); }
__device__ __forceinline__ float bf_hi(unsigned u) { return __uint_as_float(u & 0xFFFF0000u); }

__device__ __forceinline__ float lrelu(float a) { return a >= 0.f ? a : NEG * a; }

// ---------------- projection GEMM (unchanged from R2) ----------------
__global__ __launch_bounds__(256) void gemm_proj(
    const float* __restrict__ x, const float* __restrict__ W,
    const float* __restrict__ att_src, const float* __restrict__ att_dst,
    uint2* __restrict__ hp, float4* __restrict__ a_src4, float4* __restrict__ a_dst4,
    int N)
{
    const int t    = threadIdx.x;
    const int lane = t & 63;
    const int wv   = t >> 6;
    const int row0 = blockIdx.x * 32 + wv * 8;

    const float4* xp[8];
#pragma unroll
    for (int m = 0; m < 8; ++m) {
        int r = row0 + m; if (r >= N) r = N - 1;
        xp[m] = (const float4*)(x + (size_t)r * INDIM);
    }

    float acc[8][4];
#pragma unroll
    for (int m = 0; m < 8; ++m)
#pragma unroll
        for (int q = 0; q < 4; ++q) acc[m][q] = 0.f;

    for (int k4 = 0; k4 < 32; ++k4) {
        float wv4[4][4];
#pragma unroll
        for (int j = 0; j < 4; ++j) {
            const float* Wr = W + (size_t)(k4 * 4 + j) * 256 + lane;
            wv4[j][0] = Wr[0];
            wv4[j][1] = Wr[64];
            wv4[j][2] = Wr[128];
            wv4[j][3] = Wr[192];
        }
#pragma unroll
        for (int m = 0; m < 8; ++m) {
            float4 xv = xp[m][k4];
#pragma unroll
            for (int q = 0; q < 4; ++q) {
                acc[m][q] = fmaf(xv.x, wv4[0][q], acc[m][q]);
                acc[m][q] = fmaf(xv.y, wv4[1][q], acc[m][q]);
                acc[m][q] = fmaf(xv.z, wv4[2][q], acc[m][q]);
                acc[m][q] = fmaf(xv.w, wv4[3][q], acc[m][q]);
            }
        }
    }

    float asw[4], adw[4];
#pragma unroll
    for (int q = 0; q < 4; ++q) {
        asw[q] = att_src[q * CDIM + lane];
        adw[q] = att_dst[q * CDIM + lane];
    }

#pragma unroll
    for (int m = 0; m < 8; ++m) {
        int node = row0 + m;
        if (node >= N) break;
        float s0 = wave_sum(acc[m][0] * asw[0]);
        float s1 = wave_sum(acc[m][1] * asw[1]);
        float s2 = wave_sum(acc[m][2] * asw[2]);
        float s3 = wave_sum(acc[m][3] * asw[3]);
        float d0 = wave_sum(acc[m][0] * adw[0]);
        float d1 = wave_sum(acc[m][1] * adw[1]);
        float d2 = wave_sum(acc[m][2] * adw[2]);
        float d3 = wave_sum(acc[m][3] * adw[3]);
        hp[(size_t)node * CDIM + lane] =
            make_uint2(pack_bf16(acc[m][0], acc[m][1]), pack_bf16(acc[m][2], acc[m][3]));
        if (lane == 0) {
            a_src4[node] = make_float4(s0, s1, s2, s3);
            a_dst4[node] = make_float4(d0, d1, d2, d3);
        }
    }
}

// ---------------- CSR build ----------------
__global__ void k_hist(const int* __restrict__ ei, int E, int* __restrict__ deg) {
    int e = blockIdx.x * 256 + threadIdx.x;
    if (e < E) atomicAdd(&deg[ei[E + e]], 1);
}

// single-block exclusive scan over N degree counts -> off and cursor
__global__ __launch_bounds__(1024) void k_scan(const int* __restrict__ deg,
    int* __restrict__ off, int* __restrict__ cursor, int N)
{
    __shared__ int lds[1024];
    const int t = threadIdx.x;
    const int C = (N + 1023) >> 10;
    const int b = t * C;
    int sum = 0;
    for (int i = 0; i < C; ++i) {
        int idx = b + i;
        if (idx < N) sum += deg[idx];
    }
    lds[t] = sum;
    __syncthreads();
    for (int o = 1; o < 1024; o <<= 1) {
        int v = (t >= o) ? lds[t - o] : 0;
        __syncthreads();
        lds[t] += v;
        __syncthreads();
    }
    int base = (t == 0) ? 0 : lds[t - 1];
    for (int i = 0; i < C; ++i) {
        int idx = b + i;
        if (idx < N) {
            off[idx]    = base;
            cursor[idx] = base;
            base += deg[idx];
        }
    }
}

__global__ void k_scatter(const int* __restrict__ ei, int E,
    int* __restrict__ cursor, int* __restrict__ csr_src)
{
    int e = blockIdx.x * 256 + threadIdx.x;
    if (e < E) {
        int d   = ei[E + e];
        int pos = atomicAdd(&cursor[d], 1);
        csr_src[pos] = ei[e];
    }
}

// ---------------- fused aggregation + LayerNorm + PReLU ----------------
// One wave per destination node. Normalization factors out of the edge sum:
// out[d] = 0.25 * sum_h acc_h / den_h, acc_h = sum_e e_eh * h[s,h,:],
// den_h = sum_e e_eh  (incl. self-loop). Single sweep, zero atomics.
__global__ __launch_bounds__(256) void aggr_fused(
    const int* __restrict__ off, const int* __restrict__ deg,
    const int* __restrict__ csr_src,
    const float4* __restrict__ a_src4, const float4* __restrict__ a_dst4,
    const uint2* __restrict__ hp,
    const float* __restrict__ bias, const float* __restrict__ gamma,
    const float* __restrict__ beta, const float* __restrict__ prelu,
    float* __restrict__ out, int N)
{
    const int wid  = (int)((blockIdx.x * 256u + threadIdx.x) >> 6);
    const int lane = threadIdx.x & 63;
    if (wid >= N) return;
    const int d = wid;

    const float4 ad = a_dst4[d];
    float acc0 = 0.f, acc1 = 0.f, acc2 = 0.f, acc3 = 0.f;
    float den0 = 0.f, den1 = 0.f, den2 = 0.f, den3 = 0.f;

    // self-loop (s = d)
    {
        float4 as = a_src4[d];
        float e0 = __expf(lrelu(as.x + ad.x));
        float e1 = __expf(lrelu(as.y + ad.y));
        float e2 = __expf(lrelu(as.z + ad.z));
        float e3 = __expf(lrelu(as.w + ad.w));
        uint2 h2 = hp[(size_t)d * CDIM + lane];
        acc0 = e0 * bf_lo(h2.x); acc1 = e1 * bf_hi(h2.x);
        acc2 = e2 * bf_lo(h2.y); acc3 = e3 * bf_hi(h2.y);
        den0 = e0; den1 = e1; den2 = e2; den3 = e3;
    }

    const int beg = off[d];
    const int end = beg + deg[d];
    for (int j0 = beg; j0 < end; j0 += 64) {
        int navail = end - j0; if (navail > 64) navail = 64;
        int sv = (j0 + lane < end) ? csr_src[j0 + lane] : 0;
        int j = 0;
        for (; j + 1 < navail; j += 2) {
            int sA = __shfl(sv, j, 64);
            int sB = __shfl(sv, j + 1, 64);
            float4 asA = a_src4[sA];
            float4 asB = a_src4[sB];
            uint2 hA = hp[(size_t)sA * CDIM + lane];
            uint2 hB = hp[(size_t)sB * CDIM + lane];
            float eA0 = __expf(lrelu(asA.x + ad.x));
            float eA1 = __expf(lrelu(asA.y + ad.y));
            float eA2 = __expf(lrelu(asA.z + ad.z));
            float eA3 = __expf(lrelu(asA.w + ad.w));
            float eB0 = __expf(lrelu(asB.x + ad.x));
            float eB1 = __expf(lrelu(asB.y + ad.y));
            float eB2 = __expf(lrelu(asB.z + ad.z));
            float eB3 = __expf(lrelu(asB.w + ad.w));
            acc0 = fmaf(eA0, bf_lo(hA.x), acc0); acc0 = fmaf(eB0, bf_lo(hB.x), acc0);
            acc1 = fmaf(eA1, bf_hi(hA.x), acc1); acc1 = fmaf(eB1, bf_hi(hB.x), acc1);
            acc2 = fmaf(eA2, bf_lo(hA.y), acc2); acc2 = fmaf(eB2, bf_lo(hB.y), acc2);
            acc3 = fmaf(eA3, bf_hi(hA.y), acc3); acc3 = fmaf(eB3, bf_hi(hB.y), acc3);
            den0 += eA0 + eB0; den1 += eA1 + eB1;
            den2 += eA2 + eB2; den3 += eA3 + eB3;
        }
        if (j < navail) {
            int s = __shfl(sv, j, 64);
            float4 as = a_src4[s];
            uint2 h2 = hp[(size_t)s * CDIM + lane];
            float e0 = __expf(lrelu(as.x + ad.x));
            float e1 = __expf(lrelu(as.y + ad.y));
            float e2 = __expf(lrelu(as.z + ad.z));
            float e3 = __expf(lrelu(as.w + ad.w));
            acc0 = fmaf(e0, bf_lo(h2.x), acc0);
            acc1 = fmaf(e1, bf_hi(h2.x), acc1);
            acc2 = fmaf(e2, bf_lo(h2.y), acc2);
            acc3 = fmaf(e3, bf_hi(h2.y), acc3);
            den0 += e0; den1 += e1; den2 += e2; den3 += e3;
        }
    }

    float v = 0.25f * (acc0 * __builtin_amdgcn_rcpf(den0) +
                       acc1 * __builtin_amdgcn_rcpf(den1) +
                       acc2 * __builtin_amdgcn_rcpf(den2) +
                       acc3 * __builtin_amdgcn_rcpf(den3)) + bias[lane];

    float mu  = wave_sum(v) * (1.f / 64.f);
    float df  = v - mu;
    float var = wave_sum(df * df) * (1.f / 64.f);
    float rs  = rsqrtf(var + 1e-5f);
    float o   = df * rs * gamma[lane] + beta[lane];
    float pw  = prelu[0];
    o = o >= 0.f ? o : pw * o;
    out[(size_t)d * CDIM + lane] = o;
}

extern "C" void kernel_launch(void* const* d_in, const int* in_sizes, int n_in,
                              void* d_out, int out_size, void* d_ws, size_t ws_size,
                              hipStream_t stream)
{
    const float* x       = (const float*)d_in[0];
    const int*   ei      = (const int*)  d_in[1];
    const float* W       = (const float*)d_in[2];
    const float* att_src = (const float*)d_in[3];
    const float* att_dst = (const float*)d_in[4];
    const float* bias    = (const float*)d_in[5];
    const float* gamma   = (const float*)d_in[6];
    const float* beta    = (const float*)d_in[7];
    const float* prelu   = (const float*)d_in[8];

    const int N = in_sizes[0] / INDIM;
    const int E = in_sizes[1] / 2;
    float* out = (float*)d_out;

    // workspace layout
    uint2* hp     = (uint2*)d_ws;                         // N*64 uint2 (25.6 MB)
    float* a_src  = (float*)(hp + (size_t)N * CDIM);      // N*4 f
    float* a_dst  = a_src + (size_t)N * HEADS;            // N*4 f
    int*   deg    = (int*)(a_dst + (size_t)N * HEADS);    // N
    int*   off    = deg + N;                              // N
    int*   cursor = off + N;                              // N
    int*   csr    = cursor + N;                           // E

    hipMemsetAsync(deg, 0, (size_t)N * sizeof(int), stream);

    k_hist<<<(E + 255) / 256, 256, 0, stream>>>(ei, E, deg);
    k_scan<<<1, 1024, 0, stream>>>(deg, off, cursor, N);
    k_scatter<<<(E + 255) / 256, 256, 0, stream>>>(ei, E, cursor, csr);

    gemm_proj<<<(N + 31) / 32, 256, 0, stream>>>(
        x, W, att_src, att_dst, hp, (float4*)a_src, (float4*)a_dst, N);

    aggr_fused<<<(N * 64 + 255) / 256, 256, 0, stream>>>(
        off, deg, csr, (const float4*)a_src, (const float4*)a_dst, hp,
        bias, gamma, beta, prelu, out, N);
}

// Round 4
// 273.872 us; speedup vs baseline: 2.2285x; 1.4232x over previous
//
#include <hip/hip_runtime.h>

#define HEADS 4
#define CDIM  64
#define INDIM 128
#define NEG   0.2f

__device__ __forceinline__ float wave_sum(float v) {
#pragma unroll
    for (int o = 32; o > 0; o >>= 1) v += __shfl_xor(v, o, 64);
    return v;
}
__device__ __forceinline__ int wave_sum_i(int v) {
#pragma unroll
    for (int o = 32; o > 0; o >>= 1) v += __shfl_xor(v, o, 64);
    return v;
}

// pack two floats to bf16 pair (RNE), a -> low 16, b -> high 16
__device__ __forceinline__ unsigned pack_bf16(float a, float b) {
    unsigned ua = __float_as_uint(a);
    unsigned ub = __float_as_uint(b);
    ua = (ua + 0x7FFFu + ((ua >> 16) & 1u)) >> 16;
    ub = (ub + 0x7FFFu + ((ub >> 16) & 1u)) & 0xFFFF0000u;
    return ua | ub;
}
__device__ __forceinline__ float bf_lo(unsigned u) { return __uint_as_float(u << 16); }
__device__ __forceinline__ float bf_hi(unsigned u) { return __uint_as_float(u & 0xFFFF0000u); }

__device__ __forceinline__ float lrelu(float a) { return a >= 0.f ? a : NEG * a; }

// ---------------- projection GEMM ----------------
__global__ __launch_bounds__(256) void gemm_proj(
    const float* __restrict__ x, const float* __restrict__ W,
    const float* __restrict__ att_src, const float* __restrict__ att_dst,
    uint2* __restrict__ hp, float4* __restrict__ a_src4, float4* __restrict__ a_dst4,
    int N)
{
    const int t    = threadIdx.x;
    const int lane = t & 63;
    const int wv   = t >> 6;
    const int row0 = blockIdx.x * 32 + wv * 8;

    const float4* xp[8];
#pragma unroll
    for (int m = 0; m < 8; ++m) {
        int r = row0 + m; if (r >= N) r = N - 1;
        xp[m] = (const float4*)(x + (size_t)r * INDIM);
    }

    float acc[8][4];
#pragma unroll
    for (int m = 0; m < 8; ++m)
#pragma unroll
        for (int q = 0; q < 4; ++q) acc[m][q] = 0.f;

    for (int k4 = 0; k4 < 32; ++k4) {
        float wv4[4][4];
#pragma unroll
        for (int j = 0; j < 4; ++j) {
            const float* Wr = W + (size_t)(k4 * 4 + j) * 256 + lane;
            wv4[j][0] = Wr[0];
            wv4[j][1] = Wr[64];
            wv4[j][2] = Wr[128];
            wv4[j][3] = Wr[192];
        }
#pragma unroll
        for (int m = 0; m < 8; ++m) {
            float4 xv = xp[m][k4];
#pragma unroll
            for (int q = 0; q < 4; ++q) {
                acc[m][q] = fmaf(xv.x, wv4[0][q], acc[m][q]);
                acc[m][q] = fmaf(xv.y, wv4[1][q], acc[m][q]);
                acc[m][q] = fmaf(xv.z, wv4[2][q], acc[m][q]);
                acc[m][q] = fmaf(xv.w, wv4[3][q], acc[m][q]);
            }
        }
    }

    float asw[4], adw[4];
#pragma unroll
    for (int q = 0; q < 4; ++q) {
        asw[q] = att_src[q * CDIM + lane];
        adw[q] = att_dst[q * CDIM + lane];
    }

#pragma unroll
    for (int m = 0; m < 8; ++m) {
        int node = row0 + m;
        if (node >= N) break;
        float s0 = wave_sum(acc[m][0] * asw[0]);
        float s1 = wave_sum(acc[m][1] * asw[1]);
        float s2 = wave_sum(acc[m][2] * asw[2]);
        float s3 = wave_sum(acc[m][3] * asw[3]);
        float d0 = wave_sum(acc[m][0] * adw[0]);
        float d1 = wave_sum(acc[m][1] * adw[1]);
        float d2 = wave_sum(acc[m][2] * adw[2]);
        float d3 = wave_sum(acc[m][3] * adw[3]);
        hp[(size_t)node * CDIM + lane] =
            make_uint2(pack_bf16(acc[m][0], acc[m][1]), pack_bf16(acc[m][2], acc[m][3]));
        if (lane == 0) {
            a_src4[node] = make_float4(s0, s1, s2, s3);
            a_dst4[node] = make_float4(d0, d1, d2, d3);
        }
    }
}

// ---------------- CSR build ----------------
__global__ void k_hist(const int* __restrict__ ei, int E, int* __restrict__ deg) {
    int e = blockIdx.x * 256 + threadIdx.x;
    if (e < E) atomicAdd(&deg[ei[E + e]], 1);
}

// phase 1: per-block (256 elems) sums
__global__ __launch_bounds__(256) void k_scan1(const int* __restrict__ deg,
    int* __restrict__ bsum, int N)
{
    const int t = threadIdx.x, lane = t & 63, wv = t >> 6;
    int gid = blockIdx.x * 256 + t;
    int v = (gid < N) ? deg[gid] : 0;
    v = wave_sum_i(v);
    __shared__ int ws[4];
    if (lane == 0) ws[wv] = v;
    __syncthreads();
    if (t == 0) bsum[blockIdx.x] = ws[0] + ws[1] + ws[2] + ws[3];
}

// phase 2: exclusive scan of NB (<=1024) block sums, in place
__global__ __launch_bounds__(1024) void k_scan2(int* __restrict__ bsum, int NB)
{
    __shared__ int lds[1024];
    const int t = threadIdx.x;
    int v = (t < NB) ? bsum[t] : 0;
    lds[t] = v;
    __syncthreads();
    for (int o = 1; o < 1024; o <<= 1) {
        int u = (t >= o) ? lds[t - o] : 0;
        __syncthreads();
        lds[t] += u;
        __syncthreads();
    }
    if (t < NB) bsum[t] = lds[t] - v;   // exclusive
}

// phase 3: per-element exclusive scan within block + block prefix
__global__ __launch_bounds__(256) void k_scan3(const int* __restrict__ deg,
    const int* __restrict__ bsum, int* __restrict__ off, int* __restrict__ cursor,
    int N)
{
    const int t = threadIdx.x, lane = t & 63, wv = t >> 6;
    int gid = blockIdx.x * 256 + t;
    int v = (gid < N) ? deg[gid] : 0;
    int inc = v;
#pragma unroll
    for (int o = 1; o < 64; o <<= 1) {
        int u = __shfl_up(inc, o, 64);
        if (lane >= o) inc += u;
    }
    __shared__ int wtot[4];
    if (lane == 63) wtot[wv] = inc;
    __syncthreads();
    int wpre = 0;
    for (int w = 0; w < wv; ++w) wpre += wtot[w];
    int ex = inc - v + wpre + bsum[blockIdx.x];
    if (gid < N) { off[gid] = ex; cursor[gid] = ex; }
}

__global__ void k_scatter(const int* __restrict__ ei, int E,
    int* __restrict__ cursor, int* __restrict__ csr_src)
{
    int e = blockIdx.x * 256 + threadIdx.x;
    if (e < E) {
        int d   = ei[E + e];
        int pos = atomicAdd(&cursor[d], 1);
        csr_src[pos] = ei[e];
    }
}

// ---------------- fused aggregation + LayerNorm + PReLU ----------------
__global__ __launch_bounds__(256) void aggr_fused(
    const int* __restrict__ off, const int* __restrict__ deg,
    const int* __restrict__ csr_src,
    const float4* __restrict__ a_src4, const float4* __restrict__ a_dst4,
    const uint2* __restrict__ hp,
    const float* __restrict__ bias, const float* __restrict__ gamma,
    const float* __restrict__ beta, const float* __restrict__ prelu,
    float* __restrict__ out, int N)
{
    const int wid  = (int)((blockIdx.x * 256u + threadIdx.x) >> 6);
    const int lane = threadIdx.x & 63;
    if (wid >= N) return;
    const int d = wid;

    const float4 ad = a_dst4[d];
    float acc0, acc1, acc2, acc3;
    float den0, den1, den2, den3;

    // self-loop (s = d)
    {
        float4 as = a_src4[d];
        float e0 = __expf(lrelu(as.x + ad.x));
        float e1 = __expf(lrelu(as.y + ad.y));
        float e2 = __expf(lrelu(as.z + ad.z));
        float e3 = __expf(lrelu(as.w + ad.w));
        uint2 h2 = hp[(size_t)d * CDIM + lane];
        acc0 = e0 * bf_lo(h2.x); acc1 = e1 * bf_hi(h2.x);
        acc2 = e2 * bf_lo(h2.y); acc3 = e3 * bf_hi(h2.y);
        den0 = e0; den1 = e1; den2 = e2; den3 = e3;
    }

    const int beg = off[d];
    const int end = beg + deg[d];
    for (int j0 = beg; j0 < end; j0 += 64) {
        int navail = end - j0; if (navail > 64) navail = 64;
        int sv = (j0 + lane < end) ? csr_src[j0 + lane] : 0;
        int j = 0;
        for (; j + 1 < navail; j += 2) {
            int sA = __shfl(sv, j, 64);
            int sB = __shfl(sv, j + 1, 64);
            float4 asA = a_src4[sA];
            float4 asB = a_src4[sB];
            uint2 hA = hp[(size_t)sA * CDIM + lane];
            uint2 hB = hp[(size_t)sB * CDIM + lane];
            float eA0 = __expf(lrelu(asA.x + ad.x));
            float eA1 = __expf(lrelu(asA.y + ad.y));
            float eA2 = __expf(lrelu(asA.z + ad.z));
            float eA3 = __expf(lrelu(asA.w + ad.w));
            float eB0 = __expf(lrelu(asB.x + ad.x));
            float eB1 = __expf(lrelu(asB.y + ad.y));
            float eB2 = __expf(lrelu(asB.z + ad.z));
            float eB3 = __expf(lrelu(asB.w + ad.w));
            acc0 = fmaf(eA0, bf_lo(hA.x), acc0); acc0 = fmaf(eB0, bf_lo(hB.x), acc0);
            acc1 = fmaf(eA1, bf_hi(hA.x), acc1); acc1 = fmaf(eB1, bf_hi(hB.x), acc1);
            acc2 = fmaf(eA2, bf_lo(hA.y), acc2); acc2 = fmaf(eB2, bf_lo(hB.y), acc2);
            acc3 = fmaf(eA3, bf_hi(hA.y), acc3); acc3 = fmaf(eB3, bf_hi(hB.y), acc3);
            den0 += eA0 + eB0; den1 += eA1 + eB1;
            den2 += eA2 + eB2; den3 += eA3 + eB3;
        }
        if (j < navail) {
            int s = __shfl(sv, j, 64);
            float4 as = a_src4[s];
            uint2 h2 = hp[(size_t)s * CDIM + lane];
            float e0 = __expf(lrelu(as.x + ad.x));
            float e1 = __expf(lrelu(as.y + ad.y));
            float e2 = __expf(lrelu(as.z + ad.z));
            float e3 = __expf(lrelu(as.w + ad.w));
            acc0 = fmaf(e0, bf_lo(h2.x), acc0);
            acc1 = fmaf(e1, bf_hi(h2.x), acc1);
            acc2 = fmaf(e2, bf_lo(h2.y), acc2);
            acc3 = fmaf(e3, bf_hi(h2.y), acc3);
            den0 += e0; den1 += e1; den2 += e2; den3 += e3;
        }
    }

    float v = 0.25f * (acc0 * __builtin_amdgcn_rcpf(den0) +
                       acc1 * __builtin_amdgcn_rcpf(den1) +
                       acc2 * __builtin_amdgcn_rcpf(den2) +
                       acc3 * __builtin_amdgcn_rcpf(den3)) + bias[lane];

    float mu  = wave_sum(v) * (1.f / 64.f);
    float df  = v - mu;
    float var = wave_sum(df * df) * (1.f / 64.f);
    float rs  = rsqrtf(var + 1e-5f);
    float o   = df * rs * gamma[lane] + beta[lane];
    float pw  = prelu[0];
    o = o >= 0.f ? o : pw * o;
    out[(size_t)d * CDIM + lane] = o;
}

extern "C" void kernel_launch(void* const* d_in, const int* in_sizes, int n_in,
                              void* d_out, int out_size, void* d_ws, size_t ws_size,
                              hipStream_t stream)
{
    const float* x       = (const float*)d_in[0];
    const int*   ei      = (const int*)  d_in[1];
    const float* W       = (const float*)d_in[2];
    const float* att_src = (const float*)d_in[3];
    const float* att_dst = (const float*)d_in[4];
    const float* bias    = (const float*)d_in[5];
    const float* gamma   = (const float*)d_in[6];
    const float* beta    = (const float*)d_in[7];
    const float* prelu   = (const float*)d_in[8];

    const int N = in_sizes[0] / INDIM;
    const int E = in_sizes[1] / 2;
    float* out = (float*)d_out;
    const int NB = (N + 255) / 256;   // scan blocks (196 for N=50000)

    // workspace layout
    uint2* hp     = (uint2*)d_ws;                         // N*64 uint2 (25.6 MB)
    float* a_src  = (float*)(hp + (size_t)N * CDIM);      // N*4 f
    float* a_dst  = a_src + (size_t)N * HEADS;            // N*4 f
    int*   deg    = (int*)(a_dst + (size_t)N * HEADS);    // N
    int*   off    = deg + N;                              // N
    int*   cursor = off + N;                              // N
    int*   bsum   = cursor + N;                           // NB (<=1024)
    int*   csr    = bsum + 1024;                          // E

    hipMemsetAsync(deg, 0, (size_t)N * sizeof(int), stream);

    k_hist<<<(E + 255) / 256, 256, 0, stream>>>(ei, E, deg);
    k_scan1<<<NB, 256, 0, stream>>>(deg, bsum, N);
    k_scan2<<<1, 1024, 0, stream>>>(bsum, NB);
    k_scan3<<<NB, 256, 0, stream>>>(deg, bsum, off, cursor, N);
    k_scatter<<<(E + 255) / 256, 256, 0, stream>>>(ei, E, cursor, csr);

    gemm_proj<<<(N + 31) / 32, 256, 0, stream>>>(
        x, W, att_src, att_dst, hp, (float4*)a_src, (float4*)a_dst, N);

    aggr_fused<<<(N * 64 + 255) / 256, 256, 0, stream>>>(
        off, deg, csr, (const float4*)a_src, (const float4*)a_dst, hp,
        bias, gamma, beta, prelu, out, N);
}

// Round 5
// 213.298 us; speedup vs baseline: 2.8613x; 1.2840x over previous
//
#include <hip/hip_runtime.h>

#define HEADS 4
#define CDIM  64
#define INDIM 128
#define NEG   0.2f

typedef __attribute__((ext_vector_type(8))) short short8;
typedef __attribute__((ext_vector_type(4))) float f32x4;

__device__ __forceinline__ float wave_sum(float v) {
#pragma unroll
    for (int o = 32; o > 0; o >>= 1) v += __shfl_xor(v, o, 64);
    return v;
}
__device__ __forceinline__ int wave_sum_i(int v) {
#pragma unroll
    for (int o = 32; o > 0; o >>= 1) v += __shfl_xor(v, o, 64);
    return v;
}

// f32 -> bf16 bits (RNE)
__device__ __forceinline__ unsigned short f2bf(float f) {
    unsigned u = __float_as_uint(f);
    u = (u + 0x7FFFu + ((u >> 16) & 1u)) >> 16;
    return (unsigned short)u;
}
// pack two floats to bf16 pair (RNE), a -> low 16, b -> high 16
__device__ __forceinline__ unsigned pack_bf16(float a, float b) {
    unsigned ua = __float_as_uint(a);
    unsigned ub = __float_as_uint(b);
    ua = (ua + 0x7FFFu + ((ua >> 16) & 1u)) >> 16;
    ub = (ub + 0x7FFFu + ((ub >> 16) & 1u)) & 0xFFFF0000u;
    return ua | ub;
}
__device__ __forceinline__ float bf_lo(unsigned u) { return __uint_as_float(u << 16); }
__device__ __forceinline__ float bf_hi(unsigned u) { return __uint_as_float(u & 0xFFFF0000u); }

__device__ __forceinline__ float lrelu(float a) { return a >= 0.f ? a : NEG * a; }

// ---------------- Waug prep: [col][k] bf16, 272 x 128 ----------------
// cols 0..255: W[k][c]; 256..259: p_src[q][k]=sum_j W[k][q*64+j]*att_src[q][j];
// 260..263: p_dst; 264..271: zero pad.
__global__ __launch_bounds__(256) void k_prep(const float* __restrict__ W,
    const float* __restrict__ att_src, const float* __restrict__ att_dst,
    unsigned short* __restrict__ Waug)
{
    const int wv = threadIdx.x >> 6, lane = threadIdx.x & 63;
    const int c = blockIdx.x * 4 + wv;
    if (c >= 272) return;
#pragma unroll
    for (int kk = 0; kk < 2; ++kk) {
        int k = lane + kk * 64;
        float val;
        if (c < 256) {
            val = W[k * 256 + c];
        } else if (c < 260) {
            int q = c - 256; float s = 0.f;
            for (int j = 0; j < 64; ++j) s += W[k * 256 + q * 64 + j] * att_src[q * 64 + j];
            val = s;
        } else if (c < 264) {
            int q = c - 260; float s = 0.f;
            for (int j = 0; j < 64; ++j) s += W[k * 256 + q * 64 + j] * att_dst[q * 64 + j];
            val = s;
        } else {
            val = 0.f;
        }
        Waug[c * 128 + k] = f2bf(val);
    }
}

// ---------------- MFMA projection: h + logits in one pass ----------------
// 64 rows/block, 4 waves (16 rows each), all 272 cols per wave.
// B (Waug) staged to LDS [col][k] with XOR swizzle; A from global x with
// on-the-fly f32->bf16. C layout: col=lane&15, row=(lane>>4)*4+reg (m89).
__global__ __launch_bounds__(256) void gemm_mfma(
    const float* __restrict__ x, const unsigned short* __restrict__ Waug,
    uint2* __restrict__ hp, float* __restrict__ a_src, float* __restrict__ a_dst,
    int N)
{
    extern __shared__ char smem[];
    const int t = threadIdx.x;

    // stage Waug -> LDS (272*128*2B = 69632 B), 16B chunks, swizzled
    const uint4* srcw = (const uint4*)Waug;
    for (int i = t; i < 272 * 16; i += 256) {
        int col = i >> 4, kc = i & 15;
        int off = col * 256 + ((kc * 16) ^ ((col & 7) << 4));
        *(uint4*)(smem + off) = srcw[i];
    }
    __syncthreads();

    const int lane = t & 63, wv = t >> 6;
    const int l = lane & 15, g = lane >> 4;
    const int rowbase = blockIdx.x * 64 + wv * 16;

    int anode = rowbase + l; if (anode >= N) anode = N - 1;
    const float4* xrow = (const float4*)(x + (size_t)anode * INDIM);

    short8 af[4];
#pragma unroll
    for (int ks = 0; ks < 4; ++ks) {
        float4 x0 = xrow[ks * 8 + g * 2];
        float4 x1 = xrow[ks * 8 + g * 2 + 1];
        short8 a;
        a[0] = (short)f2bf(x0.x); a[1] = (short)f2bf(x0.y);
        a[2] = (short)f2bf(x0.z); a[3] = (short)f2bf(x0.w);
        a[4] = (short)f2bf(x1.x); a[5] = (short)f2bf(x1.y);
        a[6] = (short)f2bf(x1.z); a[7] = (short)f2bf(x1.w);
        af[ks] = a;
    }

    f32x4 acc[17];
    const f32x4 zero = {0.f, 0.f, 0.f, 0.f};
#pragma unroll
    for (int tt = 0; tt < 17; ++tt) acc[tt] = zero;

    const int base_b = l * 256;
#pragma unroll
    for (int ks = 0; ks < 4; ++ks) {
        const int koff = (ks * 64 + g * 16) ^ ((l & 7) << 4);
#pragma unroll
        for (int tt = 0; tt < 17; ++tt) {
            short8 bf = *(const short8*)(smem + tt * 4096 + base_b + koff);
            acc[tt] = __builtin_amdgcn_mfma_f32_16x16x32_bf16(af[ks], bf, acc[tt], 0, 0, 0);
        }
    }

    // epilogue: hp packing + logit stores
#pragma unroll
    for (int j = 0; j < 4; ++j) {
        int node = rowbase + g * 4 + j;
        if (node < N) {
#pragma unroll
            for (int u = 0; u < 4; ++u) {
                int ch = l + 16 * u;
                hp[(size_t)node * CDIM + ch] = make_uint2(
                    pack_bf16(acc[u][j],     acc[4 + u][j]),
                    pack_bf16(acc[8 + u][j], acc[12 + u][j]));
            }
            if (l < 4)      a_src[node * 4 + l]       = acc[16][j];
            else if (l < 8) a_dst[node * 4 + (l - 4)] = acc[16][j];
        }
    }
}

// ---------------- CSR build ----------------
__global__ void k_hist(const int* __restrict__ ei, int E, int* __restrict__ deg) {
    int e = blockIdx.x * 256 + threadIdx.x;
    if (e < E) atomicAdd(&deg[ei[E + e]], 1);
}

__global__ __launch_bounds__(256) void k_scan1(const int* __restrict__ deg,
    int* __restrict__ bsum, int N)
{
    const int t = threadIdx.x, lane = t & 63, wv = t >> 6;
    int gid = blockIdx.x * 256 + t;
    int v = (gid < N) ? deg[gid] : 0;
    v = wave_sum_i(v);
    __shared__ int ws[4];
    if (lane == 0) ws[wv] = v;
    __syncthreads();
    if (t == 0) bsum[blockIdx.x] = ws[0] + ws[1] + ws[2] + ws[3];
}

__global__ __launch_bounds__(1024) void k_scan2(int* __restrict__ bsum, int NB)
{
    __shared__ int lds[1024];
    const int t = threadIdx.x;
    int v = (t < NB) ? bsum[t] : 0;
    lds[t] = v;
    __syncthreads();
    for (int o = 1; o < 1024; o <<= 1) {
        int u = (t >= o) ? lds[t - o] : 0;
        __syncthreads();
        lds[t] += u;
        __syncthreads();
    }
    if (t < NB) bsum[t] = lds[t] - v;   // exclusive
}

__global__ __launch_bounds__(256) void k_scan3(const int* __restrict__ deg,
    const int* __restrict__ bsum, int* __restrict__ off, int* __restrict__ cursor,
    int N)
{
    const int t = threadIdx.x, lane = t & 63, wv = t >> 6;
    int gid = blockIdx.x * 256 + t;
    int v = (gid < N) ? deg[gid] : 0;
    int inc = v;
#pragma unroll
    for (int o = 1; o < 64; o <<= 1) {
        int u = __shfl_up(inc, o, 64);
        if (lane >= o) inc += u;
    }
    __shared__ int wtot[4];
    if (lane == 63) wtot[wv] = inc;
    __syncthreads();
    int wpre = 0;
    for (int w = 0; w < wv; ++w) wpre += wtot[w];
    int ex = inc - v + wpre + bsum[blockIdx.x];
    if (gid < N) { off[gid] = ex; cursor[gid] = ex; }
}

__global__ void k_scatter(const int* __restrict__ ei, int E,
    int* __restrict__ cursor, int* __restrict__ csr_src)
{
    int e = blockIdx.x * 256 + threadIdx.x;
    if (e < E) {
        int d   = ei[E + e];
        int pos = atomicAdd(&cursor[d], 1);
        csr_src[pos] = ei[e];
    }
}

// ---------------- fused aggregation + LayerNorm + PReLU ----------------
__global__ __launch_bounds__(256) void aggr_fused(
    const int* __restrict__ off, const int* __restrict__ deg,
    const int* __restrict__ csr_src,
    const float4* __restrict__ a_src4, const float4* __restrict__ a_dst4,
    const uint2* __restrict__ hp,
    const float* __restrict__ bias, const float* __restrict__ gamma,
    const float* __restrict__ beta, const float* __restrict__ prelu,
    float* __restrict__ out, int N)
{
    const int wid  = (int)((blockIdx.x * 256u + threadIdx.x) >> 6);
    const int lane = threadIdx.x & 63;
    if (wid >= N) return;
    const int d = wid;

    const float4 ad = a_dst4[d];
    float acc0, acc1, acc2, acc3;
    float den0, den1, den2, den3;

    // self-loop (s = d)
    {
        float4 as = a_src4[d];
        float e0 = __expf(lrelu(as.x + ad.x));
        float e1 = __expf(lrelu(as.y + ad.y));
        float e2 = __expf(lrelu(as.z + ad.z));
        float e3 = __expf(lrelu(as.w + ad.w));
        uint2 h2 = hp[(size_t)d * CDIM + lane];
        acc0 = e0 * bf_lo(h2.x); acc1 = e1 * bf_hi(h2.x);
        acc2 = e2 * bf_lo(h2.y); acc3 = e3 * bf_hi(h2.y);
        den0 = e0; den1 = e1; den2 = e2; den3 = e3;
    }

    const int beg = off[d];
    const int end = beg + deg[d];
    for (int j0 = beg; j0 < end; j0 += 64) {
        int navail = end - j0; if (navail > 64) navail = 64;
        int sv = (j0 + lane < end) ? csr_src[j0 + lane] : 0;
        int j = 0;
        for (; j + 1 < navail; j += 2) {
            int sA = __shfl(sv, j, 64);
            int sB = __shfl(sv, j + 1, 64);
            float4 asA = a_src4[sA];
            float4 asB = a_src4[sB];
            uint2 hA = hp[(size_t)sA * CDIM + lane];
            uint2 hB = hp[(size_t)sB * CDIM + lane];
            float eA0 = __expf(lrelu(asA.x + ad.x));
            float eA1 = __expf(lrelu(asA.y + ad.y));
            float eA2 = __expf(lrelu(asA.z + ad.z));
            float eA3 = __expf(lrelu(asA.w + ad.w));
            float eB0 = __expf(lrelu(asB.x + ad.x));
            float eB1 = __expf(lrelu(asB.y + ad.y));
            float eB2 = __expf(lrelu(asB.z + ad.z));
            float eB3 = __expf(lrelu(asB.w + ad.w));
            acc0 = fmaf(eA0, bf_lo(hA.x), acc0); acc0 = fmaf(eB0, bf_lo(hB.x), acc0);
            acc1 = fmaf(eA1, bf_hi(hA.x), acc1); acc1 = fmaf(eB1, bf_hi(hB.x), acc1);
            acc2 = fmaf(eA2, bf_lo(hA.y), acc2); acc2 = fmaf(eB2, bf_lo(hB.y), acc2);
            acc3 = fmaf(eA3, bf_hi(hA.y), acc3); acc3 = fmaf(eB3, bf_hi(hB.y), acc3);
            den0 += eA0 + eB0; den1 += eA1 + eB1;
            den2 += eA2 + eB2; den3 += eA3 + eB3;
        }
        if (j < navail) {
            int s = __shfl(sv, j, 64);
            float4 as = a_src4[s];
            uint2 h2 = hp[(size_t)s * CDIM + lane];
            float e0 = __expf(lrelu(as.x + ad.x));
            float e1 = __expf(lrelu(as.y + ad.y));
            float e2 = __expf(lrelu(as.z + ad.z));
            float e3 = __expf(lrelu(as.w + ad.w));
            acc0 = fmaf(e0, bf_lo(h2.x), acc0);
            acc1 = fmaf(e1, bf_hi(h2.x), acc1);
            acc2 = fmaf(e2, bf_lo(h2.y), acc2);
            acc3 = fmaf(e3, bf_hi(h2.y), acc3);
            den0 += e0; den1 += e1; den2 += e2; den3 += e3;
        }
    }

    float v = 0.25f * (acc0 * __builtin_amdgcn_rcpf(den0) +
                       acc1 * __builtin_amdgcn_rcpf(den1) +
                       acc2 * __builtin_amdgcn_rcpf(den2) +
                       acc3 * __builtin_amdgcn_rcpf(den3)) + bias[lane];

    float mu  = wave_sum(v) * (1.f / 64.f);
    float df  = v - mu;
    float var = wave_sum(df * df) * (1.f / 64.f);
    float rs  = rsqrtf(var + 1e-5f);
    float o   = df * rs * gamma[lane] + beta[lane];
    float pw  = prelu[0];
    o = o >= 0.f ? o : pw * o;
    out[(size_t)d * CDIM + lane] = o;
}

extern "C" void kernel_launch(void* const* d_in, const int* in_sizes, int n_in,
                              void* d_out, int out_size, void* d_ws, size_t ws_size,
                              hipStream_t stream)
{
    const float* x       = (const float*)d_in[0];
    const int*   ei      = (const int*)  d_in[1];
    const float* W       = (const float*)d_in[2];
    const float* att_src = (const float*)d_in[3];
    const float* att_dst = (const float*)d_in[4];
    const float* bias    = (const float*)d_in[5];
    const float* gamma   = (const float*)d_in[6];
    const float* beta    = (const float*)d_in[7];
    const float* prelu   = (const float*)d_in[8];

    const int N = in_sizes[0] / INDIM;
    const int E = in_sizes[1] / 2;
    float* out = (float*)d_out;
    const int NB = (N + 255) / 256;   // scan blocks (196 for N=50000)

    // workspace layout
    uint2* hp     = (uint2*)d_ws;                         // N*64 uint2 (25.6 MB)
    float* a_src  = (float*)(hp + (size_t)N * CDIM);      // N*4 f
    float* a_dst  = a_src + (size_t)N * HEADS;            // N*4 f
    int*   deg    = (int*)(a_dst + (size_t)N * HEADS);    // N
    int*   off    = deg + N;                              // N
    int*   cursor = off + N;                              // N
    int*   bsum   = cursor + N;                           // NB (<=1024)
    int*   csr    = bsum + 1024;                          // E
    unsigned short* Waug = (unsigned short*)(csr + E);    // 272*128 bf16

    hipMemsetAsync(deg, 0, (size_t)N * sizeof(int), stream);

    k_prep<<<68, 256, 0, stream>>>(W, att_src, att_dst, Waug);

    k_hist<<<(E + 255) / 256, 256, 0, stream>>>(ei, E, deg);
    k_scan1<<<NB, 256, 0, stream>>>(deg, bsum, N);
    k_scan2<<<1, 1024, 0, stream>>>(bsum, NB);
    k_scan3<<<NB, 256, 0, stream>>>(deg, bsum, off, cursor, N);
    k_scatter<<<(E + 255) / 256, 256, 0, stream>>>(ei, E, cursor, csr);

    gemm_mfma<<<(N + 63) / 64, 256, 69632, stream>>>(
        x, Waug, hp, a_src, a_dst, N);

    aggr_fused<<<(N * 64 + 255) / 256, 256, 0, stream>>>(
        off, deg, csr, (const float4*)a_src, (const float4*)a_dst, hp,
        bias, gamma, beta, prelu, out, N);
}

// Round 6
// 209.407 us; speedup vs baseline: 2.9145x; 1.0186x over previous
//
#include <hip/hip_runtime.h>

#define HEADS 4
#define CDIM  64
#define INDIM 128
#define NEG   0.2f

typedef __attribute__((ext_vector_type(8))) short short8;
typedef __attribute__((ext_vector_type(4))) float f32x4;

__device__ __forceinline__ float wave_sum(float v) {
#pragma unroll
    for (int o = 32; o > 0; o >>= 1) v += __shfl_xor(v, o, 64);
    return v;
}
__device__ __forceinline__ int wave_sum_i(int v) {
#pragma unroll
    for (int o = 32; o > 0; o >>= 1) v += __shfl_xor(v, o, 64);
    return v;
}

// f32 -> bf16 bits (RNE)
__device__ __forceinline__ unsigned short f2bf(float f) {
    unsigned u = __float_as_uint(f);
    u = (u + 0x7FFFu + ((u >> 16) & 1u)) >> 16;
    return (unsigned short)u;
}
// pack two floats to bf16 pair (RNE), a -> low 16, b -> high 16
__device__ __forceinline__ unsigned pack_bf16(float a, float b) {
    unsigned ua = __float_as_uint(a);
    unsigned ub = __float_as_uint(b);
    ua = (ua + 0x7FFFu + ((ua >> 16) & 1u)) >> 16;
    ub = (ub + 0x7FFFu + ((ub >> 16) & 1u)) & 0xFFFF0000u;
    return ua | ub;
}
__device__ __forceinline__ float bf_lo(unsigned u) { return __uint_as_float(u << 16); }
__device__ __forceinline__ float bf_hi(unsigned u) { return __uint_as_float(u & 0xFFFF0000u); }

__device__ __forceinline__ float lrelu(float a) { return a >= 0.f ? a : NEG * a; }

// ---------------- Waug prep: [col][k] bf16, 272 x 128 ----------------
__global__ __launch_bounds__(256) void k_prep(const float* __restrict__ W,
    const float* __restrict__ att_src, const float* __restrict__ att_dst,
    unsigned short* __restrict__ Waug)
{
    const int wv = threadIdx.x >> 6, lane = threadIdx.x & 63;
    const int c = blockIdx.x * 4 + wv;
    if (c >= 272) return;
#pragma unroll
    for (int kk = 0; kk < 2; ++kk) {
        int k = lane + kk * 64;
        float val;
        if (c < 256) {
            val = W[k * 256 + c];
        } else if (c < 260) {
            int q = c - 256; float s = 0.f;
            for (int j = 0; j < 64; ++j) s += W[k * 256 + q * 64 + j] * att_src[q * 64 + j];
            val = s;
        } else if (c < 264) {
            int q = c - 260; float s = 0.f;
            for (int j = 0; j < 64; ++j) s += W[k * 256 + q * 64 + j] * att_dst[q * 64 + j];
            val = s;
        } else {
            val = 0.f;
        }
        Waug[c * 128 + k] = f2bf(val);
    }
}

// ---------------- MFMA projection: h + logits in one pass ----------------
__global__ __launch_bounds__(256) void gemm_mfma(
    const float* __restrict__ x, const unsigned short* __restrict__ Waug,
    uint2* __restrict__ hp, float* __restrict__ a_src, float* __restrict__ a_dst,
    int N)
{
    extern __shared__ char smem[];
    const int t = threadIdx.x;

    const uint4* srcw = (const uint4*)Waug;
    for (int i = t; i < 272 * 16; i += 256) {
        int col = i >> 4, kc = i & 15;
        int off = col * 256 + ((kc * 16) ^ ((col & 7) << 4));
        *(uint4*)(smem + off) = srcw[i];
    }
    __syncthreads();

    const int lane = t & 63, wv = t >> 6;
    const int l = lane & 15, g = lane >> 4;
    const int rowbase = blockIdx.x * 64 + wv * 16;

    int anode = rowbase + l; if (anode >= N) anode = N - 1;
    const float4* xrow = (const float4*)(x + (size_t)anode * INDIM);

    short8 af[4];
#pragma unroll
    for (int ks = 0; ks < 4; ++ks) {
        float4 x0 = xrow[ks * 8 + g * 2];
        float4 x1 = xrow[ks * 8 + g * 2 + 1];
        short8 a;
        a[0] = (short)f2bf(x0.x); a[1] = (short)f2bf(x0.y);
        a[2] = (short)f2bf(x0.z); a[3] = (short)f2bf(x0.w);
        a[4] = (short)f2bf(x1.x); a[5] = (short)f2bf(x1.y);
        a[6] = (short)f2bf(x1.z); a[7] = (short)f2bf(x1.w);
        af[ks] = a;
    }

    f32x4 acc[17];
    const f32x4 zero = {0.f, 0.f, 0.f, 0.f};
#pragma unroll
    for (int tt = 0; tt < 17; ++tt) acc[tt] = zero;

    const int base_b = l * 256;
#pragma unroll
    for (int ks = 0; ks < 4; ++ks) {
        const int koff = (ks * 64 + g * 16) ^ ((l & 7) << 4);
#pragma unroll
        for (int tt = 0; tt < 17; ++tt) {
            short8 bf = *(const short8*)(smem + tt * 4096 + base_b + koff);
            acc[tt] = __builtin_amdgcn_mfma_f32_16x16x32_bf16(af[ks], bf, acc[tt], 0, 0, 0);
        }
    }

#pragma unroll
    for (int j = 0; j < 4; ++j) {
        int node = rowbase + g * 4 + j;
        if (node < N) {
#pragma unroll
            for (int u = 0; u < 4; ++u) {
                int ch = l + 16 * u;
                hp[(size_t)node * CDIM + ch] = make_uint2(
                    pack_bf16(acc[u][j],     acc[4 + u][j]),
                    pack_bf16(acc[8 + u][j], acc[12 + u][j]));
            }
            if (l < 4)      a_src[node * 4 + l]       = acc[16][j];
            else if (l < 8) a_dst[node * 4 + (l - 4)] = acc[16][j];
        }
    }
}

// ---------------- CSR build ----------------
__global__ void k_hist(const int* __restrict__ ei, int E, int* __restrict__ deg) {
    int e = blockIdx.x * 256 + threadIdx.x;
    if (e < E) atomicAdd(&deg[ei[E + e]], 1);
}

__global__ __launch_bounds__(256) void k_scan1(const int* __restrict__ deg,
    int* __restrict__ bsum, int N)
{
    const int t = threadIdx.x, lane = t & 63, wv = t >> 6;
    int gid = blockIdx.x * 256 + t;
    int v = (gid < N) ? deg[gid] : 0;
    v = wave_sum_i(v);
    __shared__ int ws[4];
    if (lane == 0) ws[wv] = v;
    __syncthreads();
    if (t == 0) bsum[blockIdx.x] = ws[0] + ws[1] + ws[2] + ws[3];
}

__global__ __launch_bounds__(1024) void k_scan2(int* __restrict__ bsum, int NB)
{
    __shared__ int lds[1024];
    const int t = threadIdx.x;
    int v = (t < NB) ? bsum[t] : 0;
    lds[t] = v;
    __syncthreads();
    for (int o = 1; o < 1024; o <<= 1) {
        int u = (t >= o) ? lds[t - o] : 0;
        __syncthreads();
        lds[t] += u;
        __syncthreads();
    }
    if (t < NB) bsum[t] = lds[t] - v;   // exclusive
}

__global__ __launch_bounds__(256) void k_scan3(const int* __restrict__ deg,
    const int* __restrict__ bsum, int* __restrict__ off, int* __restrict__ cursor,
    int N)
{
    const int t = threadIdx.x, lane = t & 63, wv = t >> 6;
    int gid = blockIdx.x * 256 + t;
    int v = (gid < N) ? deg[gid] : 0;
    int inc = v;
#pragma unroll
    for (int o = 1; o < 64; o <<= 1) {
        int u = __shfl_up(inc, o, 64);
        if (lane >= o) inc += u;
    }
    __shared__ int wtot[4];
    if (lane == 63) wtot[wv] = inc;
    __syncthreads();
    int wpre = 0;
    for (int w = 0; w < wv; ++w) wpre += wtot[w];
    int ex = inc - v + wpre + bsum[blockIdx.x];
    if (gid < N) { off[gid] = ex; cursor[gid] = ex; }
}

__global__ void k_scatter(const int* __restrict__ ei, int E,
    int* __restrict__ cursor, int* __restrict__ csr_src)
{
    int e = blockIdx.x * 256 + threadIdx.x;
    if (e < E) {
        int d   = ei[E + e];
        int pos = atomicAdd(&cursor[d], 1);
        csr_src[pos] = ei[e];
    }
}

// ---------------- fused aggregation + LayerNorm + PReLU ----------------
// One wave per destination node, lane = channel.
// Per 64-edge chunk: lane i computes exp-weights for edge i ONLY (4 exps),
// then the accumulate loop broadcasts (s, e0..e3) via shuffles (ds pipe).
// Denominators: per-lane partial sums + one wave_sum at the end.
__global__ __launch_bounds__(256) void aggr_fused(
    const int* __restrict__ off, const int* __restrict__ deg,
    const int* __restrict__ csr_src,
    const float4* __restrict__ a_src4, const float4* __restrict__ a_dst4,
    const uint2* __restrict__ hp,
    const float* __restrict__ bias, const float* __restrict__ gamma,
    const float* __restrict__ beta, const float* __restrict__ prelu,
    float* __restrict__ out, int N)
{
    const int wid  = (int)((blockIdx.x * 256u + threadIdx.x) >> 6);
    const int lane = threadIdx.x & 63;
    if (wid >= N) return;
    const int d = wid;

    const float4 ad = a_dst4[d];   // wave-uniform

    // self-loop (s = d): e_self computed by every lane (needed by all)
    float es0, es1, es2, es3;
    float acc0, acc1, acc2, acc3;
    {
        float4 as = a_src4[d];
        es0 = __expf(lrelu(as.x + ad.x));
        es1 = __expf(lrelu(as.y + ad.y));
        es2 = __expf(lrelu(as.z + ad.z));
        es3 = __expf(lrelu(as.w + ad.w));
        uint2 h2 = hp[(size_t)d * CDIM + lane];
        acc0 = es0 * bf_lo(h2.x); acc1 = es1 * bf_hi(h2.x);
        acc2 = es2 * bf_lo(h2.y); acc3 = es3 * bf_hi(h2.y);
    }
    float dl0 = 0.f, dl1 = 0.f, dl2 = 0.f, dl3 = 0.f;  // per-lane denom partials

    const int beg = off[d];
    const int end = beg + deg[d];
    for (int j0 = beg; j0 < end; j0 += 64) {
        int navail = end - j0; if (navail > 64) navail = 64;
        const bool valid = (j0 + lane < end);
        int sv = valid ? csr_src[j0 + lane] : 0;
        // per-lane exp for own edge (scattered 16B gather)
        float4 as = a_src4[sv];
        float le0 = valid ? __expf(lrelu(as.x + ad.x)) : 0.f;
        float le1 = valid ? __expf(lrelu(as.y + ad.y)) : 0.f;
        float le2 = valid ? __expf(lrelu(as.z + ad.z)) : 0.f;
        float le3 = valid ? __expf(lrelu(as.w + ad.w)) : 0.f;
        dl0 += le0; dl1 += le1; dl2 += le2; dl3 += le3;

        int j = 0;
        for (; j + 3 < navail; j += 4) {
            int sA = __shfl(sv, j, 64);
            int sB = __shfl(sv, j + 1, 64);
            int sC = __shfl(sv, j + 2, 64);
            int sD = __shfl(sv, j + 3, 64);
            uint2 hA = hp[(size_t)sA * CDIM + lane];
            uint2 hB = hp[(size_t)sB * CDIM + lane];
            uint2 hC = hp[(size_t)sC * CDIM + lane];
            uint2 hD = hp[(size_t)sD * CDIM + lane];
            float eA0 = __shfl(le0, j, 64), eA1 = __shfl(le1, j, 64);
            float eA2 = __shfl(le2, j, 64), eA3 = __shfl(le3, j, 64);
            float eB0 = __shfl(le0, j + 1, 64), eB1 = __shfl(le1, j + 1, 64);
            float eB2 = __shfl(le2, j + 1, 64), eB3 = __shfl(le3, j + 1, 64);
            float eC0 = __shfl(le0, j + 2, 64), eC1 = __shfl(le1, j + 2, 64);
            float eC2 = __shfl(le2, j + 2, 64), eC3 = __shfl(le3, j + 2, 64);
            float eD0 = __shfl(le0, j + 3, 64), eD1 = __shfl(le1, j + 3, 64);
            float eD2 = __shfl(le2, j + 3, 64), eD3 = __shfl(le3, j + 3, 64);
            acc0 = fmaf(eA0, bf_lo(hA.x), acc0);
            acc1 = fmaf(eA1, bf_hi(hA.x), acc1);
            acc2 = fmaf(eA2, bf_lo(hA.y), acc2);
            acc3 = fmaf(eA3, bf_hi(hA.y), acc3);
            acc0 = fmaf(eB0, bf_lo(hB.x), acc0);
            acc1 = fmaf(eB1, bf_hi(hB.x), acc1);
            acc2 = fmaf(eB2, bf_lo(hB.y), acc2);
            acc3 = fmaf(eB3, bf_hi(hB.y), acc3);
            acc0 = fmaf(eC0, bf_lo(hC.x), acc0);
            acc1 = fmaf(eC1, bf_hi(hC.x), acc1);
            acc2 = fmaf(eC2, bf_lo(hC.y), acc2);
            acc3 = fmaf(eC3, bf_hi(hC.y), acc3);
            acc0 = fmaf(eD0, bf_lo(hD.x), acc0);
            acc1 = fmaf(eD1, bf_hi(hD.x), acc1);
            acc2 = fmaf(eD2, bf_lo(hD.y), acc2);
            acc3 = fmaf(eD3, bf_hi(hD.y), acc3);
        }
        for (; j < navail; ++j) {
            int s = __shfl(sv, j, 64);
            uint2 h2 = hp[(size_t)s * CDIM + lane];
            float e0 = __shfl(le0, j, 64), e1 = __shfl(le1, j, 64);
            float e2 = __shfl(le2, j, 64), e3 = __shfl(le3, j, 64);
            acc0 = fmaf(e0, bf_lo(h2.x), acc0);
            acc1 = fmaf(e1, bf_hi(h2.x), acc1);
            acc2 = fmaf(e2, bf_lo(h2.y), acc2);
            acc3 = fmaf(e3, bf_hi(h2.y), acc3);
        }
    }

    // denominators: edge sums + self-loop
    float den0 = wave_sum(dl0) + es0;
    float den1 = wave_sum(dl1) + es1;
    float den2 = wave_sum(dl2) + es2;
    float den3 = wave_sum(dl3) + es3;

    float v = 0.25f * (acc0 * __builtin_amdgcn_rcpf(den0) +
                       acc1 * __builtin_amdgcn_rcpf(den1) +
                       acc2 * __builtin_amdgcn_rcpf(den2) +
                       acc3 * __builtin_amdgcn_rcpf(den3)) + bias[lane];

    float mu  = wave_sum(v) * (1.f / 64.f);
    float df  = v - mu;
    float var = wave_sum(df * df) * (1.f / 64.f);
    float rs  = rsqrtf(var + 1e-5f);
    float o   = df * rs * gamma[lane] + beta[lane];
    float pw  = prelu[0];
    o = o >= 0.f ? o : pw * o;
    out[(size_t)d * CDIM + lane] = o;
}

extern "C" void kernel_launch(void* const* d_in, const int* in_sizes, int n_in,
                              void* d_out, int out_size, void* d_ws, size_t ws_size,
                              hipStream_t stream)
{
    const float* x       = (const float*)d_in[0];
    const int*   ei      = (const int*)  d_in[1];
    const float* W       = (const float*)d_in[2];
    const float* att_src = (const float*)d_in[3];
    const float* att_dst = (const float*)d_in[4];
    const float* bias    = (const float*)d_in[5];
    const float* gamma   = (const float*)d_in[6];
    const float* beta    = (const float*)d_in[7];
    const float* prelu   = (const float*)d_in[8];

    const int N = in_sizes[0] / INDIM;
    const int E = in_sizes[1] / 2;
    float* out = (float*)d_out;
    const int NB = (N + 255) / 256;

    // workspace layout
    uint2* hp     = (uint2*)d_ws;                         // N*64 uint2 (25.6 MB)
    float* a_src  = (float*)(hp + (size_t)N * CDIM);      // N*4 f
    float* a_dst  = a_src + (size_t)N * HEADS;            // N*4 f
    int*   deg    = (int*)(a_dst + (size_t)N * HEADS);    // N
    int*   off    = deg + N;                              // N
    int*   cursor = off + N;                              // N
    int*   bsum   = cursor + N;                           // NB (<=1024)
    int*   csr    = bsum + 1024;                          // E
    unsigned short* Waug = (unsigned short*)(csr + E);    // 272*128 bf16

    hipMemsetAsync(deg, 0, (size_t)N * sizeof(int), stream);

    k_prep<<<68, 256, 0, stream>>>(W, att_src, att_dst, Waug);

    k_hist<<<(E + 255) / 256, 256, 0, stream>>>(ei, E, deg);
    k_scan1<<<NB, 256, 0, stream>>>(deg, bsum, N);
    k_scan2<<<1, 1024, 0, stream>>>(bsum, NB);
    k_scan3<<<NB, 256, 0, stream>>>(deg, bsum, off, cursor, N);
    k_scatter<<<(E + 255) / 256, 256, 0, stream>>>(ei, E, cursor, csr);

    gemm_mfma<<<(N + 63) / 64, 256, 69632, stream>>>(
        x, Waug, hp, a_src, a_dst, N);

    aggr_fused<<<(N * 64 + 255) / 256, 256, 0, stream>>>(
        off, deg, csr, (const float4*)a_src, (const float4*)a_dst, hp,
        bias, gamma, beta, prelu, out, N);
}

// Round 8
// 207.792 us; speedup vs baseline: 2.9371x; 1.0078x over previous
//
#include <hip/hip_runtime.h>

#define HEADS 4
#define CDIM  64
#define INDIM 128
#define NEG   0.2f
#define CAP   256   // LDS edge slots per wave

typedef __attribute__((ext_vector_type(8))) short short8;
typedef __attribute__((ext_vector_type(4))) float f32x4;
typedef _Float16 half2_t __attribute__((ext_vector_type(2)));

__device__ __forceinline__ float wave_sum(float v) {
#pragma unroll
    for (int o = 32; o > 0; o >>= 1) v += __shfl_xor(v, o, 64);
    return v;
}
__device__ __forceinline__ int wave_sum_i(int v) {
#pragma unroll
    for (int o = 32; o > 0; o >>= 1) v += __shfl_xor(v, o, 64);
    return v;
}

// f32 -> bf16 bits (RNE) — for the MFMA operand prep only
__device__ __forceinline__ unsigned short f2bf(float f) {
    unsigned u = __float_as_uint(f);
    u = (u + 0x7FFFu + ((u >> 16) & 1u)) >> 16;
    return (unsigned short)u;
}

__device__ __forceinline__ unsigned pk_f16(float a, float b) {
    auto h = __builtin_amdgcn_cvt_pkrtz(a, b);   // __fp16 x2
    return __builtin_bit_cast(unsigned, h);
}
__device__ __forceinline__ half2_t as_h2(unsigned u) {
    return __builtin_bit_cast(half2_t, u);
}

#if __has_builtin(__builtin_amdgcn_fdot2)
__device__ __forceinline__ float fdot2(unsigned a, unsigned b, float c) {
    return __builtin_amdgcn_fdot2(as_h2(a), as_h2(b), c, false);
}
#else
__device__ __forceinline__ float fdot2(unsigned a, unsigned b, float c) {
    half2_t ha = as_h2(a), hb = as_h2(b);
    return c + (float)ha.x * (float)hb.x + (float)ha.y * (float)hb.y;
}
#endif

__device__ __forceinline__ float lrelu(float a) { return a >= 0.f ? a : NEG * a; }

// ---------------- Waug prep: [col][k] bf16, 272 x 128 ----------------
__global__ __launch_bounds__(256) void k_prep(const float* __restrict__ W,
    const float* __restrict__ att_src, const float* __restrict__ att_dst,
    unsigned short* __restrict__ Waug)
{
    const int wv = threadIdx.x >> 6, lane = threadIdx.x & 63;
    const int c = blockIdx.x * 4 + wv;
    if (c >= 272) return;
#pragma unroll
    for (int kk = 0; kk < 2; ++kk) {
        int k = lane + kk * 64;
        float val;
        if (c < 256) {
            val = W[k * 256 + c];
        } else if (c < 260) {
            int q = c - 256; float s = 0.f;
            for (int j = 0; j < 64; ++j) s += W[k * 256 + q * 64 + j] * att_src[q * 64 + j];
            val = s;
        } else if (c < 264) {
            int q = c - 260; float s = 0.f;
            for (int j = 0; j < 64; ++j) s += W[k * 256 + q * 64 + j] * att_dst[q * 64 + j];
            val = s;
        } else {
            val = 0.f;
        }
        Waug[c * 128 + k] = f2bf(val);
    }
}

// ---------------- MFMA projection: h (f16-packed) + logits ----------------
__global__ __launch_bounds__(256) void gemm_mfma(
    const float* __restrict__ x, const unsigned short* __restrict__ Waug,
    uint2* __restrict__ hp, float* __restrict__ a_src, float* __restrict__ a_dst,
    int N)
{
    extern __shared__ char smem[];
    const int t = threadIdx.x;

    const uint4* srcw = (const uint4*)Waug;
    for (int i = t; i < 272 * 16; i += 256) {
        int col = i >> 4, kc = i & 15;
        int off = col * 256 + ((kc * 16) ^ ((col & 7) << 4));
        *(uint4*)(smem + off) = srcw[i];
    }
    __syncthreads();

    const int lane = t & 63, wv = t >> 6;
    const int l = lane & 15, g = lane >> 4;
    const int rowbase = blockIdx.x * 64 + wv * 16;

    int anode = rowbase + l; if (anode >= N) anode = N - 1;
    const float4* xrow = (const float4*)(x + (size_t)anode * INDIM);

    short8 af[4];
#pragma unroll
    for (int ks = 0; ks < 4; ++ks) {
        float4 x0 = xrow[ks * 8 + g * 2];
        float4 x1 = xrow[ks * 8 + g * 2 + 1];
        short8 a;
        a[0] = (short)f2bf(x0.x); a[1] = (short)f2bf(x0.y);
        a[2] = (short)f2bf(x0.z); a[3] = (short)f2bf(x0.w);
        a[4] = (short)f2bf(x1.x); a[5] = (short)f2bf(x1.y);
        a[6] = (short)f2bf(x1.z); a[7] = (short)f2bf(x1.w);
        af[ks] = a;
    }

    f32x4 acc[17];
    const f32x4 zero = {0.f, 0.f, 0.f, 0.f};
#pragma unroll
    for (int tt = 0; tt < 17; ++tt) acc[tt] = zero;

    const int base_b = l * 256;
#pragma unroll
    for (int ks = 0; ks < 4; ++ks) {
        const int koff = (ks * 64 + g * 16) ^ ((l & 7) << 4);
#pragma unroll
        for (int tt = 0; tt < 17; ++tt) {
            short8 bf = *(const short8*)(smem + tt * 4096 + base_b + koff);
            acc[tt] = __builtin_amdgcn_mfma_f32_16x16x32_bf16(af[ks], bf, acc[tt], 0, 0, 0);
        }
    }

#pragma unroll
    for (int j = 0; j < 4; ++j) {
        int node = rowbase + g * 4 + j;
        if (node < N) {
#pragma unroll
            for (int u = 0; u < 4; ++u) {
                int ch = l + 16 * u;
                hp[(size_t)node * CDIM + ch] = make_uint2(
                    pk_f16(acc[u][j],     acc[4 + u][j]),
                    pk_f16(acc[8 + u][j], acc[12 + u][j]));
            }
            if (l < 4)      a_src[node * 4 + l]       = acc[16][j];
            else if (l < 8) a_dst[node * 4 + (l - 4)] = acc[16][j];
        }
    }
}

// ---------------- CSR build ----------------
__global__ void k_hist(const int* __restrict__ ei, int E, int* __restrict__ deg) {
    int e = blockIdx.x * 256 + threadIdx.x;
    if (e < E) atomicAdd(&deg[ei[E + e]], 1);
}

__global__ __launch_bounds__(256) void k_scan1(const int* __restrict__ deg,
    int* __restrict__ bsum, int N)
{
    const int t = threadIdx.x, lane = t & 63, wv = t >> 6;
    int gid = blockIdx.x * 256 + t;
    int v = (gid < N) ? deg[gid] : 0;
    v = wave_sum_i(v);
    __shared__ int ws[4];
    if (lane == 0) ws[wv] = v;
    __syncthreads();
    if (t == 0) bsum[blockIdx.x] = ws[0] + ws[1] + ws[2] + ws[3];
}

__global__ __launch_bounds__(1024) void k_scan2(int* __restrict__ bsum, int NB)
{
    __shared__ int lds[1024];
    const int t = threadIdx.x;
    int v = (t < NB) ? bsum[t] : 0;
    lds[t] = v;
    __syncthreads();
    for (int o = 1; o < 1024; o <<= 1) {
        int u = (t >= o) ? lds[t - o] : 0;
        __syncthreads();
        lds[t] += u;
        __syncthreads();
    }
    if (t < NB) bsum[t] = lds[t] - v;   // exclusive
}

__global__ __launch_bounds__(256) void k_scan3(const int* __restrict__ deg,
    const int* __restrict__ bsum, int* __restrict__ off, int* __restrict__ cursor,
    int N)
{
    const int t = threadIdx.x, lane = t & 63, wv = t >> 6;
    int gid = blockIdx.x * 256 + t;
    int v = (gid < N) ? deg[gid] : 0;
    int inc = v;
#pragma unroll
    for (int o = 1; o < 64; o <<= 1) {
        int u = __shfl_up(inc, o, 64);
        if (lane >= o) inc += u;
    }
    __shared__ int wtot[4];
    if (lane == 63) wtot[wv] = inc;
    __syncthreads();
    int wpre = 0;
    for (int w = 0; w < wv; ++w) wpre += wtot[w];
    int ex = inc - v + wpre + bsum[blockIdx.x];
    if (gid < N) { off[gid] = ex; cursor[gid] = ex; }
}

__global__ void k_scatter(const int* __restrict__ ei, int E,
    int* __restrict__ cursor, int* __restrict__ csr_src)
{
    int e = blockIdx.x * 256 + threadIdx.x;
    if (e < E) {
        int d   = ei[E + e];
        int pos = atomicAdd(&cursor[d], 1);
        csr_src[pos] = ei[e];
    }
}

// ---------------- fused aggregation + LayerNorm + PReLU ----------------
// One wave per destination node. Phase A: owner-lane computes raw exps,
// stages {e01,e23,sv} (f16-packed) in LDS, accumulates denom partials.
// After wave_sum denoms, owner-lane rescale folds 1/den into the weights.
// Phase B: per edge = 1 uniform ds_read_b128 + 1 hp gather + 2 v_dot2_f32_f16.
__global__ __launch_bounds__(256) void aggr_fused(
    const int* __restrict__ off, const int* __restrict__ deg,
    const int* __restrict__ csr_src,
    const float4* __restrict__ a_src4, const float4* __restrict__ a_dst4,
    const uint2* __restrict__ hp,
    const float* __restrict__ bias, const float* __restrict__ gamma,
    const float* __restrict__ beta, const float* __restrict__ prelu,
    float* __restrict__ out, int N)
{
    __shared__ uint4 slot[4][CAP];
    const int wv   = threadIdx.x >> 6;
    const int lane = threadIdx.x & 63;
    const int wid  = (int)(blockIdx.x * 4u + wv);
    if (wid >= N) return;
    const int d = wid;
    uint4* sl = slot[wv];

    const float4 ad = a_dst4[d];   // wave-uniform
    const int deg_d = deg[d];
    const int beg   = off[d];
    const int nv    = deg_d < CAP ? deg_d : CAP;

    // ---- Phase A: raw exps -> LDS, denom partials ----
    float dl0 = 0.f, dl1 = 0.f, dl2 = 0.f, dl3 = 0.f;
    for (int base = 0; base < deg_d; base += 64) {
        int j = base + lane;
        bool valid = j < deg_d;
        int sv = valid ? csr_src[beg + j] : 0;
        float4 as = a_src4[sv];
        float e0 = valid ? __expf(lrelu(as.x + ad.x)) : 0.f;
        float e1 = valid ? __expf(lrelu(as.y + ad.y)) : 0.f;
        float e2 = valid ? __expf(lrelu(as.z + ad.z)) : 0.f;
        float e3 = valid ? __expf(lrelu(as.w + ad.w)) : 0.f;
        dl0 += e0; dl1 += e1; dl2 += e2; dl3 += e3;
        if (j < CAP) sl[j] = make_uint4(pk_f16(e0, e1), pk_f16(e2, e3), (unsigned)sv, 0u);
    }

    // self-loop exps (wave-uniform)
    float4 asd = a_src4[d];
    float es0 = __expf(lrelu(asd.x + ad.x));
    float es1 = __expf(lrelu(asd.y + ad.y));
    float es2 = __expf(lrelu(asd.z + ad.z));
    float es3 = __expf(lrelu(asd.w + ad.w));

    float r0 = __builtin_amdgcn_rcpf(wave_sum(dl0) + es0);
    float r1 = __builtin_amdgcn_rcpf(wave_sum(dl1) + es1);
    float r2 = __builtin_amdgcn_rcpf(wave_sum(dl2) + es2);
    float r3 = __builtin_amdgcn_rcpf(wave_sum(dl3) + es3);

    // ---- rescale pass: w = e * r (owner lane) ----
    for (int base = 0; base < nv; base += 64) {
        int j = base + lane;
        if (j < nv) {
            uint2 ev = *(const uint2*)&sl[j];
            half2_t e01 = as_h2(ev.x), e23 = as_h2(ev.y);
            *(uint2*)&sl[j] = make_uint2(
                pk_f16((float)e01.x * r0, (float)e01.y * r1),
                pk_f16((float)e23.x * r2, (float)e23.y * r3));
        }
    }
    __builtin_amdgcn_wave_barrier();

    // ---- Phase B: accumulate (self-loop init) ----
    uint2 hd = hp[(size_t)d * CDIM + lane];
    unsigned pw01 = pk_f16(es0 * r0, es1 * r1);
    unsigned pw23 = pk_f16(es2 * r2, es3 * r3);
    float acc01 = fdot2(pw01, hd.x, 0.f);
    float acc23 = fdot2(pw23, hd.y, 0.f);

    int j = 0;
    for (; j + 3 < nv; j += 4) {
        uint4 t0 = sl[j], t1 = sl[j + 1], t2 = sl[j + 2], t3 = sl[j + 3];
        uint2 h0 = hp[(size_t)t0.z * CDIM + lane];
        uint2 h1 = hp[(size_t)t1.z * CDIM + lane];
        uint2 h2 = hp[(size_t)t2.z * CDIM + lane];
        uint2 h3 = hp[(size_t)t3.z * CDIM + lane];
        acc01 = fdot2(t0.x, h0.x, acc01); acc23 = fdot2(t0.y, h0.y, acc23);
        acc01 = fdot2(t1.x, h1.x, acc01); acc23 = fdot2(t1.y, h1.y, acc23);
        acc01 = fdot2(t2.x, h2.x, acc01); acc23 = fdot2(t2.y, h2.y, acc23);
        acc01 = fdot2(t3.x, h3.x, acc01); acc23 = fdot2(t3.y, h3.y, acc23);
    }
    for (; j < nv; ++j) {
        uint4 t0 = sl[j];
        uint2 h0 = hp[(size_t)t0.z * CDIM + lane];
        acc01 = fdot2(t0.x, h0.x, acc01);
        acc23 = fdot2(t0.y, h0.y, acc23);
    }

    // ---- slow path: deg > CAP (recompute with known r) ----
    for (int base = CAP; base < deg_d; base += 64) {
        int jj = base + lane;
        bool valid = jj < deg_d;
        int sv = valid ? csr_src[beg + jj] : 0;
        float4 as = a_src4[sv];
        float e0 = valid ? __expf(lrelu(as.x + ad.x)) : 0.f;
        float e1 = valid ? __expf(lrelu(as.y + ad.y)) : 0.f;
        float e2 = valid ? __expf(lrelu(as.z + ad.z)) : 0.f;
        float e3 = valid ? __expf(lrelu(as.w + ad.w)) : 0.f;
        sl[lane] = make_uint4(pk_f16(e0 * r0, e1 * r1), pk_f16(e2 * r2, e3 * r3),
                              (unsigned)sv, 0u);
        __builtin_amdgcn_wave_barrier();
        int nav = deg_d - base; if (nav > 64) nav = 64;
        for (int q = 0; q < nav; ++q) {
            uint4 t0 = sl[q];
            uint2 h0 = hp[(size_t)t0.z * CDIM + lane];
            acc01 = fdot2(t0.x, h0.x, acc01);
            acc23 = fdot2(t0.y, h0.y, acc23);
        }
        __builtin_amdgcn_wave_barrier();
    }

    // ---- epilogue: mean over heads + bias + LN + PReLU ----
    float v = 0.25f * (acc01 + acc23) + bias[lane];
    float mu  = wave_sum(v) * (1.f / 64.f);
    float df  = v - mu;
    float var = wave_sum(df * df) * (1.f / 64.f);
    float rs  = rsqrtf(var + 1e-5f);
    float o   = df * rs * gamma[lane] + beta[lane];
    float pw  = prelu[0];
    o = o >= 0.f ? o : pw * o;
    out[(size_t)d * CDIM + lane] = o;
}

extern "C" void kernel_launch(void* const* d_in, const int* in_sizes, int n_in,
                              void* d_out, int out_size, void* d_ws, size_t ws_size,
                              hipStream_t stream)
{
    const float* x       = (const float*)d_in[0];
    const int*   ei      = (const int*)  d_in[1];
    const float* W       = (const float*)d_in[2];
    const float* att_src = (const float*)d_in[3];
    const float* att_dst = (const float*)d_in[4];
    const float* bias    = (const float*)d_in[5];
    const float* gamma   = (const float*)d_in[6];
    const float* beta    = (const float*)d_in[7];
    const float* prelu   = (const float*)d_in[8];

    const int N = in_sizes[0] / INDIM;
    const int E = in_sizes[1] / 2;
    float* out = (float*)d_out;
    const int NB = (N + 255) / 256;

    // workspace layout
    uint2* hp     = (uint2*)d_ws;                         // N*64 uint2 (25.6 MB)
    float* a_src  = (float*)(hp + (size_t)N * CDIM);      // N*4 f
    float* a_dst  = a_src + (size_t)N * HEADS;            // N*4 f
    int*   deg    = (int*)(a_dst + (size_t)N * HEADS);    // N
    int*   off    = deg + N;                              // N
    int*   cursor = off + N;                              // N
    int*   bsum   = cursor + N;                           // NB (<=1024)
    int*   csr    = bsum + 1024;                          // E
    unsigned short* Waug = (unsigned short*)(csr + E);    // 272*128 bf16

    (void)hipMemsetAsync(deg, 0, (size_t)N * sizeof(int), stream);

    k_prep<<<68, 256, 0, stream>>>(W, att_src, att_dst, Waug);

    k_hist<<<(E + 255) / 256, 256, 0, stream>>>(ei, E, deg);
    k_scan1<<<NB, 256, 0, stream>>>(deg, bsum, N);
    k_scan2<<<1, 1024, 0, stream>>>(bsum, NB);
    k_scan3<<<NB, 256, 0, stream>>>(deg, bsum, off, cursor, N);
    k_scatter<<<(E + 255) / 256, 256, 0, stream>>>(ei, E, cursor, csr);

    gemm_mfma<<<(N + 63) / 64, 256, 69632, stream>>>(
        x, Waug, hp, a_src, a_dst, N);

    aggr_fused<<<(N + 3) / 4, 256, 0, stream>>>(
        off, deg, csr, (const float4*)a_src, (const float4*)a_dst, hp,
        bias, gamma, beta, prelu, out, N);
}

// Round 9
// 193.314 us; speedup vs baseline: 3.1571x; 1.0749x over previous
//
#include <hip/hip_runtime.h>

#define HEADS 4
#define CDIM  64
#define INDIM 128
#define NEG   0.2f
#define CAP     256   // LDS edge slots per wave
#define FASTCAP 252   // fast-path edge limit (leaves pad room to CAP)

typedef __attribute__((ext_vector_type(8))) short short8;
typedef __attribute__((ext_vector_type(4))) float f32x4;
typedef _Float16 half2_t __attribute__((ext_vector_type(2)));

__device__ __forceinline__ float wave_sum(float v) {
#pragma unroll
    for (int o = 32; o > 0; o >>= 1) v += __shfl_xor(v, o, 64);
    return v;
}
__device__ __forceinline__ int wave_sum_i(int v) {
#pragma unroll
    for (int o = 32; o > 0; o >>= 1) v += __shfl_xor(v, o, 64);
    return v;
}

// f32 -> bf16 bits (RNE) — for the MFMA operand prep only
__device__ __forceinline__ unsigned short f2bf(float f) {
    unsigned u = __float_as_uint(f);
    u = (u + 0x7FFFu + ((u >> 16) & 1u)) >> 16;
    return (unsigned short)u;
}

__device__ __forceinline__ unsigned pk_f16(float a, float b) {
    auto h = __builtin_amdgcn_cvt_pkrtz(a, b);   // __fp16 x2
    return __builtin_bit_cast(unsigned, h);
}
__device__ __forceinline__ half2_t as_h2(unsigned u) {
    return __builtin_bit_cast(half2_t, u);
}

#if __has_builtin(__builtin_amdgcn_fdot2)
__device__ __forceinline__ float fdot2(unsigned a, unsigned b, float c) {
    return __builtin_amdgcn_fdot2(as_h2(a), as_h2(b), c, false);
}
#else
__device__ __forceinline__ float fdot2(unsigned a, unsigned b, float c) {
    half2_t ha = as_h2(a), hb = as_h2(b);
    return c + (float)ha.x * (float)hb.x + (float)ha.y * (float)hb.y;
}
#endif

__device__ __forceinline__ float lrelu(float a) { return a >= 0.f ? a : NEG * a; }

// ---------------- Waug prep (+ deg zeroing): [col][k] bf16, 272 x 128 ----------------
__global__ __launch_bounds__(256) void k_prep(const float* __restrict__ W,
    const float* __restrict__ att_src, const float* __restrict__ att_dst,
    unsigned short* __restrict__ Waug, int* __restrict__ deg, int N)
{
    // fold the deg memset in (saves one launch)
    for (int i = blockIdx.x * 256 + threadIdx.x; i < N; i += 68 * 256) deg[i] = 0;

    const int wv = threadIdx.x >> 6, lane = threadIdx.x & 63;
    const int c = blockIdx.x * 4 + wv;
    if (c >= 272) return;
#pragma unroll
    for (int kk = 0; kk < 2; ++kk) {
        int k = lane + kk * 64;
        float val;
        if (c < 256) {
            val = W[k * 256 + c];
        } else if (c < 260) {
            int q = c - 256; float s = 0.f;
            for (int j = 0; j < 64; ++j) s += W[k * 256 + q * 64 + j] * att_src[q * 64 + j];
            val = s;
        } else if (c < 264) {
            int q = c - 260; float s = 0.f;
            for (int j = 0; j < 64; ++j) s += W[k * 256 + q * 64 + j] * att_dst[q * 64 + j];
            val = s;
        } else {
            val = 0.f;
        }
        Waug[c * 128 + k] = f2bf(val);
    }
}

// ---------------- MFMA projection: h (f16-packed) + logits ----------------
// 512 threads, 8 waves, 128 rows/block -> 2 blocks/CU = 16 waves/CU.
__global__ __launch_bounds__(512) void gemm_mfma(
    const float* __restrict__ x, const unsigned short* __restrict__ Waug,
    uint2* __restrict__ hp, float* __restrict__ a_src, float* __restrict__ a_dst,
    int N)
{
    extern __shared__ char smem[];
    const int t = threadIdx.x;

    const uint4* srcw = (const uint4*)Waug;
    for (int i = t; i < 272 * 16; i += 512) {
        int col = i >> 4, kc = i & 15;
        int off = col * 256 + ((kc * 16) ^ ((col & 7) << 4));
        *(uint4*)(smem + off) = srcw[i];
    }
    __syncthreads();

    const int lane = t & 63, wv = t >> 6;
    const int l = lane & 15, g = lane >> 4;
    const int rowbase = blockIdx.x * 128 + wv * 16;

    int anode = rowbase + l; if (anode >= N) anode = N - 1;
    const float4* xrow = (const float4*)(x + (size_t)anode * INDIM);

    short8 af[4];
#pragma unroll
    for (int ks = 0; ks < 4; ++ks) {
        float4 x0 = xrow[ks * 8 + g * 2];
        float4 x1 = xrow[ks * 8 + g * 2 + 1];
        short8 a;
        a[0] = (short)f2bf(x0.x); a[1] = (short)f2bf(x0.y);
        a[2] = (short)f2bf(x0.z); a[3] = (short)f2bf(x0.w);
        a[4] = (short)f2bf(x1.x); a[5] = (short)f2bf(x1.y);
        a[6] = (short)f2bf(x1.z); a[7] = (short)f2bf(x1.w);
        af[ks] = a;
    }

    f32x4 acc[17];
    const f32x4 zero = {0.f, 0.f, 0.f, 0.f};
#pragma unroll
    for (int tt = 0; tt < 17; ++tt) acc[tt] = zero;

    const int base_b = l * 256;
#pragma unroll
    for (int ks = 0; ks < 4; ++ks) {
        const int koff = (ks * 64 + g * 16) ^ ((l & 7) << 4);
#pragma unroll
        for (int tt = 0; tt < 17; ++tt) {
            short8 bf = *(const short8*)(smem + tt * 4096 + base_b + koff);
            acc[tt] = __builtin_amdgcn_mfma_f32_16x16x32_bf16(af[ks], bf, acc[tt], 0, 0, 0);
        }
    }

#pragma unroll
    for (int j = 0; j < 4; ++j) {
        int node = rowbase + g * 4 + j;
        if (node < N) {
#pragma unroll
            for (int u = 0; u < 4; ++u) {
                int ch = l + 16 * u;
                hp[(size_t)node * CDIM + ch] = make_uint2(
                    pk_f16(acc[u][j],     acc[4 + u][j]),
                    pk_f16(acc[8 + u][j], acc[12 + u][j]));
            }
            if (l < 4)      a_src[node * 4 + l]       = acc[16][j];
            else if (l < 8) a_dst[node * 4 + (l - 4)] = acc[16][j];
        }
    }
}

// ---------------- CSR build ----------------
__global__ void k_hist(const int* __restrict__ ei, int E, int* __restrict__ deg) {
    int e = blockIdx.x * 256 + threadIdx.x;
    if (e < E) atomicAdd(&deg[ei[E + e]], 1);
}

__global__ __launch_bounds__(256) void k_scan1(const int* __restrict__ deg,
    int* __restrict__ bsum, int N)
{
    const int t = threadIdx.x, lane = t & 63, wv = t >> 6;
    int gid = blockIdx.x * 256 + t;
    int v = (gid < N) ? deg[gid] : 0;
    v = wave_sum_i(v);
    __shared__ int ws[4];
    if (lane == 0) ws[wv] = v;
    __syncthreads();
    if (t == 0) bsum[blockIdx.x] = ws[0] + ws[1] + ws[2] + ws[3];
}

__global__ __launch_bounds__(1024) void k_scan2(int* __restrict__ bsum, int NB)
{
    __shared__ int lds[1024];
    const int t = threadIdx.x;
    int v = (t < NB) ? bsum[t] : 0;
    lds[t] = v;
    __syncthreads();
    for (int o = 1; o < 1024; o <<= 1) {
        int u = (t >= o) ? lds[t - o] : 0;
        __syncthreads();
        lds[t] += u;
        __syncthreads();
    }
    if (t < NB) bsum[t] = lds[t] - v;   // exclusive
}

__global__ __launch_bounds__(256) void k_scan3(const int* __restrict__ deg,
    const int* __restrict__ bsum, int* __restrict__ off, int* __restrict__ cursor,
    int N)
{
    const int t = threadIdx.x, lane = t & 63, wv = t >> 6;
    int gid = blockIdx.x * 256 + t;
    int v = (gid < N) ? deg[gid] : 0;
    int inc = v;
#pragma unroll
    for (int o = 1; o < 64; o <<= 1) {
        int u = __shfl_up(inc, o, 64);
        if (lane >= o) inc += u;
    }
    __shared__ int wtot[4];
    if (lane == 63) wtot[wv] = inc;
    __syncthreads();
    int wpre = 0;
    for (int w = 0; w < wv; ++w) wpre += wtot[w];
    int ex = inc - v + wpre + bsum[blockIdx.x];
    if (gid < N) { off[gid] = ex; cursor[gid] = ex; }
}

__global__ void k_scatter(const int* __restrict__ ei, int E,
    int* __restrict__ cursor, int* __restrict__ csr_src)
{
    int e = blockIdx.x * 256 + threadIdx.x;
    if (e < E) {
        int d   = ei[E + e];
        int pos = atomicAdd(&cursor[d], 1);
        csr_src[pos] = ei[e];
    }
}

// ---------------- fused aggregation + LayerNorm + PReLU ----------------
// Phase A: owner-lane raw exps -> LDS slots, denom partials.
// Rescale: fold 1/den in; pad slots to multiple of 4 with zero-weight entries.
// Phase B: register-double-buffered: next slots (ds) AND next gathers (vmem)
// issued before consuming current -> 4 gathers always in flight per wave.
__global__ __launch_bounds__(256) void aggr_fused(
    const int* __restrict__ off, const int* __restrict__ deg,
    const int* __restrict__ csr_src,
    const float4* __restrict__ a_src4, const float4* __restrict__ a_dst4,
    const uint2* __restrict__ hp,
    const float* __restrict__ bias, const float* __restrict__ gamma,
    const float* __restrict__ beta, const float* __restrict__ prelu,
    float* __restrict__ out, int N)
{
    __shared__ uint4 slot[4][CAP];
    const int wv   = threadIdx.x >> 6;
    const int lane = threadIdx.x & 63;
    const int wid  = (int)(blockIdx.x * 4u + wv);
    if (wid >= N) return;
    const int d = wid;
    uint4* sl = slot[wv];

    const float4 ad = a_dst4[d];   // wave-uniform
    const int deg_d = deg[d];
    const int beg   = off[d];
    const int nv    = deg_d < FASTCAP ? deg_d : FASTCAP;
    const int nv4   = (nv + 3) & ~3;

    // ---- Phase A: raw exps -> LDS, denom partials ----
    float dl0 = 0.f, dl1 = 0.f, dl2 = 0.f, dl3 = 0.f;
    for (int base = 0; base < deg_d; base += 64) {
        int j = base + lane;
        bool valid = j < deg_d;
        int sv = valid ? csr_src[beg + j] : 0;
        float4 as = a_src4[sv];
        float e0 = valid ? __expf(lrelu(as.x + ad.x)) : 0.f;
        float e1 = valid ? __expf(lrelu(as.y + ad.y)) : 0.f;
        float e2 = valid ? __expf(lrelu(as.z + ad.z)) : 0.f;
        float e3 = valid ? __expf(lrelu(as.w + ad.w)) : 0.f;
        dl0 += e0; dl1 += e1; dl2 += e2; dl3 += e3;
        if (j < CAP) sl[j] = make_uint4(pk_f16(e0, e1), pk_f16(e2, e3), (unsigned)sv, 0u);
    }

    // self-loop exps (wave-uniform)
    float4 asd = a_src4[d];
    float es0 = __expf(lrelu(asd.x + ad.x));
    float es1 = __expf(lrelu(asd.y + ad.y));
    float es2 = __expf(lrelu(asd.z + ad.z));
    float es3 = __expf(lrelu(asd.w + ad.w));

    float r0 = __builtin_amdgcn_rcpf(wave_sum(dl0) + es0);
    float r1 = __builtin_amdgcn_rcpf(wave_sum(dl1) + es1);
    float r2 = __builtin_amdgcn_rcpf(wave_sum(dl2) + es2);
    float r3 = __builtin_amdgcn_rcpf(wave_sum(dl3) + es3);

    // ---- rescale pass: w = e * r (owner lane); pad [nv, nv4) with zeros ----
    for (int base = 0; base < nv4; base += 64) {
        int j = base + lane;
        if (j < nv) {
            uint2 ev = *(const uint2*)&sl[j];
            half2_t e01 = as_h2(ev.x), e23 = as_h2(ev.y);
            *(uint2*)&sl[j] = make_uint2(
                pk_f16((float)e01.x * r0, (float)e01.y * r1),
                pk_f16((float)e23.x * r2, (float)e23.y * r3));
        } else if (j < nv4) {
            sl[j] = make_uint4(0u, 0u, 0u, 0u);   // zero weight, sv=0 -> no-op
        }
    }
    __builtin_amdgcn_wave_barrier();

    // ---- Phase B: accumulate (self-loop init) ----
    uint2 hd = hp[(size_t)d * CDIM + lane];
    unsigned pw01 = pk_f16(es0 * r0, es1 * r1);
    unsigned pw23 = pk_f16(es2 * r2, es3 * r3);
    float acc01 = fdot2(pw01, hd.x, 0.f);
    float acc23 = fdot2(pw23, hd.y, 0.f);

    if (nv4 >= 8) {
        uint4 c0 = sl[0], c1 = sl[1], c2 = sl[2], c3 = sl[3];
        uint2 h0 = hp[(size_t)c0.z * CDIM + lane];
        uint2 h1 = hp[(size_t)c1.z * CDIM + lane];
        uint2 h2 = hp[(size_t)c2.z * CDIM + lane];
        uint2 h3 = hp[(size_t)c3.z * CDIM + lane];
        int j = 0;
        for (; j + 7 < nv4; j += 4) {
            uint4 n0 = sl[j + 4], n1 = sl[j + 5], n2 = sl[j + 6], n3 = sl[j + 7];
            uint2 g0 = hp[(size_t)n0.z * CDIM + lane];
            uint2 g1 = hp[(size_t)n1.z * CDIM + lane];
            uint2 g2 = hp[(size_t)n2.z * CDIM + lane];
            uint2 g3 = hp[(size_t)n3.z * CDIM + lane];
            acc01 = fdot2(c0.x, h0.x, acc01); acc23 = fdot2(c0.y, h0.y, acc23);
            acc01 = fdot2(c1.x, h1.x, acc01); acc23 = fdot2(c1.y, h1.y, acc23);
            acc01 = fdot2(c2.x, h2.x, acc01); acc23 = fdot2(c2.y, h2.y, acc23);
            acc01 = fdot2(c3.x, h3.x, acc01); acc23 = fdot2(c3.y, h3.y, acc23);
            c0 = n0; c1 = n1; c2 = n2; c3 = n3;
            h0 = g0; h1 = g1; h2 = g2; h3 = g3;
        }
        acc01 = fdot2(c0.x, h0.x, acc01); acc23 = fdot2(c0.y, h0.y, acc23);
        acc01 = fdot2(c1.x, h1.x, acc01); acc23 = fdot2(c1.y, h1.y, acc23);
        acc01 = fdot2(c2.x, h2.x, acc01); acc23 = fdot2(c2.y, h2.y, acc23);
        acc01 = fdot2(c3.x, h3.x, acc01); acc23 = fdot2(c3.y, h3.y, acc23);
    } else if (nv4 == 4) {
        uint4 c0 = sl[0], c1 = sl[1], c2 = sl[2], c3 = sl[3];
        uint2 h0 = hp[(size_t)c0.z * CDIM + lane];
        uint2 h1 = hp[(size_t)c1.z * CDIM + lane];
        uint2 h2 = hp[(size_t)c2.z * CDIM + lane];
        uint2 h3 = hp[(size_t)c3.z * CDIM + lane];
        acc01 = fdot2(c0.x, h0.x, acc01); acc23 = fdot2(c0.y, h0.y, acc23);
        acc01 = fdot2(c1.x, h1.x, acc01); acc23 = fdot2(c1.y, h1.y, acc23);
        acc01 = fdot2(c2.x, h2.x, acc01); acc23 = fdot2(c2.y, h2.y, acc23);
        acc01 = fdot2(c3.x, h3.x, acc01); acc23 = fdot2(c3.y, h3.y, acc23);
    }

    // ---- slow path: deg > FASTCAP (recompute with known r) ----
    for (int base = FASTCAP; base < deg_d; base += 64) {
        int jj = base + lane;
        bool valid = jj < deg_d;
        int sv = valid ? csr_src[beg + jj] : 0;
        float4 as = a_src4[sv];
        float e0 = valid ? __expf(lrelu(as.x + ad.x)) : 0.f;
        float e1 = valid ? __expf(lrelu(as.y + ad.y)) : 0.f;
        float e2 = valid ? __expf(lrelu(as.z + ad.z)) : 0.f;
        float e3 = valid ? __expf(lrelu(as.w + ad.w)) : 0.f;
        sl[lane] = make_uint4(pk_f16(e0 * r0, e1 * r1), pk_f16(e2 * r2, e3 * r3),
                              (unsigned)sv, 0u);
        __builtin_amdgcn_wave_barrier();
        int nav = deg_d - base; if (nav > 64) nav = 64;
        for (int q = 0; q < nav; ++q) {
            uint4 t0 = sl[q];
            uint2 h0 = hp[(size_t)t0.z * CDIM + lane];
            acc01 = fdot2(t0.x, h0.x, acc01);
            acc23 = fdot2(t0.y, h0.y, acc23);
        }
        __builtin_amdgcn_wave_barrier();
    }

    // ---- epilogue: mean over heads + bias + LN + PReLU ----
    float v = 0.25f * (acc01 + acc23) + bias[lane];
    float mu  = wave_sum(v) * (1.f / 64.f);
    float df  = v - mu;
    float var = wave_sum(df * df) * (1.f / 64.f);
    float rs  = rsqrtf(var + 1e-5f);
    float o   = df * rs * gamma[lane] + beta[lane];
    float pw  = prelu[0];
    o = o >= 0.f ? o : pw * o;
    out[(size_t)d * CDIM + lane] = o;
}

extern "C" void kernel_launch(void* const* d_in, const int* in_sizes, int n_in,
                              void* d_out, int out_size, void* d_ws, size_t ws_size,
                              hipStream_t stream)
{
    const float* x       = (const float*)d_in[0];
    const int*   ei      = (const int*)  d_in[1];
    const float* W       = (const float*)d_in[2];
    const float* att_src = (const float*)d_in[3];
    const float* att_dst = (const float*)d_in[4];
    const float* bias    = (const float*)d_in[5];
    const float* gamma   = (const float*)d_in[6];
    const float* beta    = (const float*)d_in[7];
    const float* prelu   = (const float*)d_in[8];

    const int N = in_sizes[0] / INDIM;
    const int E = in_sizes[1] / 2;
    float* out = (float*)d_out;
    const int NB = (N + 255) / 256;

    // workspace layout
    uint2* hp     = (uint2*)d_ws;                         // N*64 uint2 (25.6 MB)
    float* a_src  = (float*)(hp + (size_t)N * CDIM);      // N*4 f
    float* a_dst  = a_src + (size_t)N * HEADS;            // N*4 f
    int*   deg    = (int*)(a_dst + (size_t)N * HEADS);    // N
    int*   off    = deg + N;                              // N
    int*   cursor = off + N;                              // N
    int*   bsum   = cursor + N;                           // NB (<=1024)
    int*   csr    = bsum + 1024;                          // E
    unsigned short* Waug = (unsigned short*)(csr + E);    // 272*128 bf16

    k_prep<<<68, 256, 0, stream>>>(W, att_src, att_dst, Waug, deg, N);

    k_hist<<<(E + 255) / 256, 256, 0, stream>>>(ei, E, deg);
    k_scan1<<<NB, 256, 0, stream>>>(deg, bsum, N);
    k_scan2<<<1, 1024, 0, stream>>>(bsum, NB);
    k_scan3<<<NB, 256, 0, stream>>>(deg, bsum, off, cursor, N);
    k_scatter<<<(E + 255) / 256, 256, 0, stream>>>(ei, E, cursor, csr);

    gemm_mfma<<<(N + 127) / 128, 512, 69632, stream>>>(
        x, Waug, hp, a_src, a_dst, N);

    aggr_fused<<<(N + 3) / 4, 256, 0, stream>>>(
        off, deg, csr, (const float4*)a_src, (const float4*)a_dst, hp,
        bias, gamma, beta, prelu, out, N);
}